// Round 1
// baseline (1034.842 us; speedup 1.0000x reference)
//
#include <hip/hip_runtime.h>

// LCSA: dilated local-window self-attention, fp32 baseline.
// B=2, L=1024, D=512, H=8, HEAD_W=64, KERNEL=16, dilations {1,1,2,2,4,4,8,8},
// MODE=forward -> src(l,k) = l - (15-k)*dil, zero-padded outside [0,L).

#define BD 2
#define LL 1024
#define DM 512
#define HH 8
#define KT 16   // KERNEL taps
#define HW 64   // head width

__constant__ int c_dil[8] = {1, 1, 2, 2, 4, 4, 8, 8};

// ---------------------------------------------------------------------------
// Generic C = A * B^T + bias GEMM ("NT": both row-major with contiguous K).
// A: M x Kd, Bm: N x Kd, C: M x N, bias: N. Tiles 64x64, K-step 16,
// 256 threads, 4x4 micro-tile/thread. M,N,Kd assumed multiples of 64/16.
// ---------------------------------------------------------------------------
__global__ __launch_bounds__(256, 2) void gemm_nt_bias(
    const float* __restrict__ A, const float* __restrict__ Bm,
    const float* __restrict__ bias, float* __restrict__ C,
    int M, int N, int Kd)
{
    __shared__ float As[16][68];   // [k][row], +pad breaks bank conflicts
    __shared__ float Bs[16][68];

    const int tid = threadIdx.x;
    const int tx  = tid & 15;          // output col group
    const int ty  = tid >> 4;          // output row group
    const int r0  = blockIdx.y << 6;
    const int c0  = blockIdx.x << 6;
    const int lr  = tid >> 2;          // staging row 0..63
    const int k4  = (tid & 3) << 2;    // staging k offset 0,4,8,12

    const float* Ap = A  + (size_t)(r0 + lr) * Kd + k4;
    const float* Bp = Bm + (size_t)(c0 + lr) * Kd + k4;

    float acc[4][4];
#pragma unroll
    for (int i = 0; i < 4; ++i)
#pragma unroll
        for (int j = 0; j < 4; ++j) acc[i][j] = 0.f;

    for (int d0 = 0; d0 < Kd; d0 += 16) {
        float4 av = *(const float4*)(Ap + d0);
        float4 bv = *(const float4*)(Bp + d0);
        As[k4 + 0][lr] = av.x; As[k4 + 1][lr] = av.y;
        As[k4 + 2][lr] = av.z; As[k4 + 3][lr] = av.w;
        Bs[k4 + 0][lr] = bv.x; Bs[k4 + 1][lr] = bv.y;
        Bs[k4 + 2][lr] = bv.z; Bs[k4 + 3][lr] = bv.w;
        __syncthreads();
#pragma unroll
        for (int dd = 0; dd < 16; ++dd) {
            float4 a4 = *(const float4*)&As[dd][ty << 2];
            float4 b4 = *(const float4*)&Bs[dd][tx << 2];
            float ar[4] = {a4.x, a4.y, a4.z, a4.w};
            float br[4] = {b4.x, b4.y, b4.z, b4.w};
#pragma unroll
            for (int i = 0; i < 4; ++i)
#pragma unroll
                for (int j = 0; j < 4; ++j)
                    acc[i][j] = fmaf(ar[i], br[j], acc[i][j]);
        }
        __syncthreads();
    }

#pragma unroll
    for (int i = 0; i < 4; ++i) {
        float4 o;
        const int c = c0 + (tx << 2);
        o.x = acc[i][0] + bias[c + 0];
        o.y = acc[i][1] + bias[c + 1];
        o.z = acc[i][2] + bias[c + 2];
        o.w = acc[i][3] + bias[c + 3];
        *(float4*)&C[(size_t)(r0 + (ty << 2) + i) * N + c] = o;
    }
}

// ---------------------------------------------------------------------------
// 64(l) x 64(o) x 512(d) tile GEMM used per k-tap inside attn_kernel.
// A rows are x[src + row] (zero when out of range), B rows are W[o].
// ---------------------------------------------------------------------------
__device__ __forceinline__ void tile_gemm(
    const float* __restrict__ xb, int src, bool ok,
    const float* __restrict__ wrow,   // W + (o=lr)*DM + k4
    int lr, int k4, int tx, int ty,
    float (&As)[16][68], float (&Ws)[16][68], float (&acc)[4][4])
{
#pragma unroll
    for (int i = 0; i < 4; ++i)
#pragma unroll
        for (int j = 0; j < 4; ++j) acc[i][j] = 0.f;

    const float* xrow = xb + (size_t)(ok ? src : 0) * DM + k4;

    for (int d0 = 0; d0 < DM; d0 += 16) {
        float4 av = make_float4(0.f, 0.f, 0.f, 0.f);
        if (ok) av = *(const float4*)(xrow + d0);
        float4 wv = *(const float4*)(wrow + d0);
        As[k4 + 0][lr] = av.x; As[k4 + 1][lr] = av.y;
        As[k4 + 2][lr] = av.z; As[k4 + 3][lr] = av.w;
        Ws[k4 + 0][lr] = wv.x; Ws[k4 + 1][lr] = wv.y;
        Ws[k4 + 2][lr] = wv.z; Ws[k4 + 3][lr] = wv.w;
        __syncthreads();
#pragma unroll
        for (int dd = 0; dd < 16; ++dd) {
            float4 a4 = *(const float4*)&As[dd][ty << 2];
            float4 b4 = *(const float4*)&Ws[dd][tx << 2];
            float ar[4] = {a4.x, a4.y, a4.z, a4.w};
            float br[4] = {b4.x, b4.y, b4.z, b4.w};
#pragma unroll
            for (int i = 0; i < 4; ++i)
#pragma unroll
                for (int j = 0; j < 4; ++j)
                    acc[i][j] = fmaf(ar[i], br[j], acc[i][j]);
        }
        __syncthreads();
    }
}

// ---------------------------------------------------------------------------
// Fused K/V projection + attention per (b, h, 64-l tile).
// grid = B*H*(L/64) = 256 blocks, 256 threads.
// Low 3 bits of blockIdx = head, so each head's Wk+Wv (4 MB) pins to one XCD L2.
// ---------------------------------------------------------------------------
__global__ __launch_bounds__(256, 2) void attn_kernel(
    const float* __restrict__ x,     // (B,L,D)
    const float* __restrict__ q,     // (B,L,H,HW) from gemm_nt_bias
    const float* __restrict__ Wk,    // (H,KT,HW,D)
    const float* __restrict__ bk,    // (H,KT,HW)
    const float* __restrict__ Wv,
    const float* __restrict__ bv,
    float* __restrict__ attn)        // (B,L,H,HW)
{
    __shared__ float As[16][68];
    __shared__ float Ws[16][68];
    __shared__ float qs[64][68];
    __shared__ float lg[64][17];     // logits -> scores, [l][k]
    __shared__ float red[64][17];    // partial q.k reduction, [l][tx]

    const int tid = threadIdx.x;
    const int tx  = tid & 15;
    const int ty  = tid >> 4;
    const int bid = blockIdx.x;
    const int h   = bid & 7;
    const int t   = (bid >> 3) & 15;
    const int b   = bid >> 7;
    const int l0  = t << 6;
    const int dil = c_dil[h];
    const int lr  = tid >> 2;
    const int k4  = (tid & 3) << 2;

    // stage q tile (64 l x 64 o)
    for (int i = tid; i < 64 * 16; i += 256) {
        int l = i >> 4, o4 = (i & 15) << 2;
        float4 v = *(const float4*)&q[((size_t)(b * LL + l0 + l) * HH + h) * HW + o4];
        *(float4*)&qs[l][o4] = v;
    }

    const float* xb  = x  + (size_t)b * LL * DM;
    const float* Wkh = Wk + (size_t)h * KT * HW * DM;
    const float* Wvh = Wv + (size_t)h * KT * HW * DM;
    const float* bkh = bk + h * KT * HW;
    const float* bvh = bv + h * KT * HW;

    float acc[4][4];

    // ---- K phase: logits[l][kk] ----
    for (int kk = 0; kk < KT; ++kk) {
        const int src = l0 + lr - (KT - 1 - kk) * dil;
        const bool ok = (src >= 0) && (src < LL);
        tile_gemm(xb, src, ok, Wkh + (size_t)(kk * HW + lr) * DM + k4,
                  lr, k4, tx, ty, As, Ws, acc);
        const float* bkp = bkh + kk * HW + (tx << 2);
#pragma unroll
        for (int i = 0; i < 4; ++i) {
            float p = 0.f;
#pragma unroll
            for (int j = 0; j < 4; ++j)
                p += (acc[i][j] + bkp[j]) * qs[(ty << 2) + i][(tx << 2) + j];
            red[(ty << 2) + i][tx] = p;
        }
        __syncthreads();
        if (tid < 64) {
            float s = 0.f;
#pragma unroll
            for (int u = 0; u < 16; ++u) s += red[tid][u];
            lg[tid][kk] = s;
        }
        __syncthreads();
    }

    // ---- softmax over the 16 taps ----
    if (tid < 64) {
        float m = lg[tid][0];
#pragma unroll
        for (int u = 1; u < KT; ++u) m = fmaxf(m, lg[tid][u]);
        float s = 0.f;
#pragma unroll
        for (int u = 0; u < KT; ++u) {
            float e = expf(lg[tid][u] - m);
            lg[tid][u] = e;
            s += e;
        }
        float inv = 1.f / s;
#pragma unroll
        for (int u = 0; u < KT; ++u) lg[tid][u] *= inv;
    }
    __syncthreads();

    // ---- V phase: attn[l][o] = sum_k score * (vproj + bv) ----
    float vacc[4][4];
#pragma unroll
    for (int i = 0; i < 4; ++i)
#pragma unroll
        for (int j = 0; j < 4; ++j) vacc[i][j] = 0.f;

    for (int kk = 0; kk < KT; ++kk) {
        const int src = l0 + lr - (KT - 1 - kk) * dil;
        const bool ok = (src >= 0) && (src < LL);
        tile_gemm(xb, src, ok, Wvh + (size_t)(kk * HW + lr) * DM + k4,
                  lr, k4, tx, ty, As, Ws, acc);
        const float* bvp = bvh + kk * HW + (tx << 2);
#pragma unroll
        for (int i = 0; i < 4; ++i) {
            float sc = lg[(ty << 2) + i][kk];
#pragma unroll
            for (int j = 0; j < 4; ++j)
                vacc[i][j] = fmaf(sc, acc[i][j] + bvp[j], vacc[i][j]);
        }
    }

    // write attn / sqrt(HW); layout (B,L,H,HW) so final GEMM is plain NT
#pragma unroll
    for (int i = 0; i < 4; ++i) {
        float4 o;
        o.x = vacc[i][0] * 0.125f;
        o.y = vacc[i][1] * 0.125f;
        o.z = vacc[i][2] * 0.125f;
        o.w = vacc[i][3] * 0.125f;
        *(float4*)&attn[((size_t)(b * LL + l0 + (ty << 2) + i) * HH + h) * HW + (tx << 2)] = o;
    }
}

// ---------------------------------------------------------------------------
extern "C" void kernel_launch(void* const* d_in, const int* in_sizes, int n_in,
                              void* d_out, int out_size, void* d_ws, size_t ws_size,
                              hipStream_t stream)
{
    const float* x  = (const float*)d_in[0];
    const float* Wq = (const float*)d_in[1];
    const float* bq = (const float*)d_in[2];
    const float* Wk = (const float*)d_in[3];
    const float* bk = (const float*)d_in[4];
    const float* Wv = (const float*)d_in[5];
    const float* bv = (const float*)d_in[6];
    const float* Wo = (const float*)d_in[7];
    const float* bo = (const float*)d_in[8];
    float* out = (float*)d_out;

    float* qws = (float*)d_ws;                       // (B,L,H,HW) = 4 MB
    float* aws = qws + (size_t)BD * LL * HH * HW;    // (B,L,H,HW) = 4 MB

    const int M = BD * LL;   // 2048

    // Q = X * Wq^T + bq   (Wq flattens to (H*HW, D) row-major)
    gemm_nt_bias<<<dim3((HH * HW) / 64, M / 64), 256, 0, stream>>>(
        x, Wq, bq, qws, M, HH * HW, DM);

    // fused dilated-window attention (K/V proj + softmax + weighted sum)
    attn_kernel<<<BD * HH * (LL / 64), 256, 0, stream>>>(
        x, qws, Wk, bk, Wv, bv, aws);

    // out = attn * Wo^T + bo   (Wo flattens to (D, H*HW) row-major)
    gemm_nt_bias<<<dim3(DM / 64, M / 64), 256, 0, stream>>>(
        aws, Wo, bo, out, M, DM, HH * HW);
}

// Round 2
// 211.691 us; speedup vs baseline: 4.8885x; 4.8885x over previous
//
#include <hip/hip_runtime.h>

// LCSA: dilated local-window self-attention.
// B=2, L=1024, D=512, H=8, HEAD_W=64, KERNEL=16, dilations {1,1,2,2,4,4,8,8},
// MODE=forward -> src(l,k) = l - (15-k)*dil, zero-padded outside [0,L).
//
// Fast path (needs ~91 MB ws):
//   cvt: fp32->bf16 for x, Wq, Wk, Wv, Wo (Wk/Wv adjacent => one 16384x512 B)
//   gemm_bf16 mode1: q   = x*Wq^T + bq          (bf16 out, row-major)
//   gemm_bf16 mode2: k/v = x*[Wk;Wv]^T + bk/bv  (bf16 out, scattered (b,h,k,l,o))
//   attn_bf16:       gather + softmax + weighted sum (OOB tap -> bias row)
//   gemm_bf16 mode0: out = attn*Wo^T + bo       (fp32 out)
// Fallback: round-1 fp32 path (8 MB ws).

#define BD 2
#define LL 1024
#define DM 512
#define HH 8
#define KT 16
#define HW 64

typedef unsigned short u16;
typedef unsigned int u32;
typedef __bf16 bf16x8 __attribute__((ext_vector_type(8)));
typedef float f32x4 __attribute__((ext_vector_type(4)));
typedef unsigned short ushort4v __attribute__((ext_vector_type(4)));
typedef unsigned short ushort8v __attribute__((ext_vector_type(8)));

__constant__ int c_dil[8] = {1, 1, 2, 2, 4, 4, 8, 8};

__device__ __forceinline__ float bf2f(u16 u) {
    return __builtin_bit_cast(float, (u32)u << 16);
}
__device__ __forceinline__ u16 f2bf(float f) {   // round-to-nearest-even
    u32 u = __builtin_bit_cast(u32, f);
    return (u16)((u + 0x7fffu + ((u >> 16) & 1u)) >> 16);
}

// async global->LDS, 16 B per lane; lds dest must be (uniform base + lane*16)
__device__ __forceinline__ void gl_lds16(const u16* g, u16* l) {
    __builtin_amdgcn_global_load_lds(
        (__attribute__((address_space(1))) void*)g,
        (__attribute__((address_space(3))) void*)l, 16, 0, 0);
}

// ===========================================================================
// bf16 NT GEMM, 128x128 tile, BK=32, 256 thr (4 waves, 64x64 each),
// 16x16x32 MFMA. M,N mult of 128, K mult of 32.
// mode 0: C0 fp32 row-major + bias0
// mode 1: C0 bf16 row-major + bias0
// mode 2: kv scatter: col n<8192 -> C0(kbuf)+bias0, else C1(vbuf)+bias1;
//         dst[((b*8+h)*16+k)*1024+l)*64+o], b=row>>10,l=row&1023,
//         h=(n&8191)>>10, k=(n>>6)&15, o=n&63
// ===========================================================================
__global__ __launch_bounds__(256, 3) void gemm_bf16(
    const u16* __restrict__ A, const u16* __restrict__ Bm,
    int M, int N, int K,
    const float* __restrict__ bias0, const float* __restrict__ bias1,
    void* __restrict__ C0, void* __restrict__ C1, int mode)
{
    __shared__ u16 As[128 * 32];
    __shared__ u16 Bs[128 * 32];

    const int tid  = threadIdx.x;
    const int wave = tid >> 6, lane = tid & 63;
    const int m0 = blockIdx.y << 7, n0 = blockIdx.x << 7;
    const int r0 = tid >> 2;            // staging row 0..63 (round 0)
    const int cc = (tid & 3) << 3;      // staging k-offset (elements)
    const int mw = (wave >> 1) << 6;    // wave's 64x64 sub-tile
    const int nw = (wave & 1) << 6;
    const int q8 = (lane >> 4) << 3;    // frag k-group
    const int lr = lane & 15;           // frag row/col within 16

    const u16* Ag = A  + (size_t)(m0 + r0) * K + cc;
    const u16* Bg = Bm + (size_t)(n0 + r0) * K + cc;
    u16* lA = &As[0] + tid * 8;         // byte offset tid*16 = wave*1024+lane*16
    u16* lB = &Bs[0] + tid * 8;

    f32x4 acc[4][4];
#pragma unroll
    for (int i = 0; i < 4; ++i)
#pragma unroll
        for (int j = 0; j < 4; ++j) acc[i][j] = (f32x4){0.f, 0.f, 0.f, 0.f};

    for (int k0 = 0; k0 < K; k0 += 32) {
        gl_lds16(Ag + k0, lA);
        gl_lds16(Ag + k0 + (size_t)64 * K, lA + 64 * 32);
        gl_lds16(Bg + k0, lB);
        gl_lds16(Bg + k0 + (size_t)64 * K, lB + 64 * 32);
        __syncthreads();

        bf16x8 af[4], bfr[4];
#pragma unroll
        for (int i = 0; i < 4; ++i)
            af[i] = *(const bf16x8*)&As[(mw + (i << 4) + lr) * 32 + q8];
#pragma unroll
        for (int j = 0; j < 4; ++j)
            bfr[j] = *(const bf16x8*)&Bs[(nw + (j << 4) + lr) * 32 + q8];
#pragma unroll
        for (int i = 0; i < 4; ++i)
#pragma unroll
            for (int j = 0; j < 4; ++j)
                acc[i][j] = __builtin_amdgcn_mfma_f32_16x16x32_bf16(
                    af[i], bfr[j], acc[i][j], 0, 0, 0);
        __syncthreads();
    }

    // epilogue: C row = m0+mw+16i+(lane>>4)*4+r, col = n0+nw+16j+(lane&15)
#pragma unroll
    for (int i = 0; i < 4; ++i) {
        const int rowb = m0 + mw + (i << 4) + ((lane >> 4) << 2);
#pragma unroll
        for (int j = 0; j < 4; ++j) {
            const int col = n0 + nw + (j << 4) + lr;
#pragma unroll
            for (int r = 0; r < 4; ++r) {
                const float v = acc[i][j][r];
                const int row = rowb + r;
                if (mode == 0) {
                    ((float*)C0)[(size_t)row * N + col] = v + bias0[col];
                } else if (mode == 1) {
                    ((u16*)C0)[(size_t)row * N + col] = f2bf(v + bias0[col]);
                } else {
                    const int b = row >> 10, l = row & 1023;
                    const int nl = col & 8191;
                    const float bs = (col < 8192) ? bias0[nl] : bias1[nl];
                    u16* dst = (col < 8192) ? (u16*)C0 : (u16*)C1;
                    const size_t off =
                        ((((size_t)b * HH + (nl >> 10)) * KT + ((nl >> 6) & 15)) * LL + l) * HW
                        + (nl & 63);
                    dst[off] = f2bf(v + bs);
                }
            }
        }
    }
}

// ===========================================================================
// fp32 -> bf16 conversion for x, Wq, Wk, Wv, Wo (one float4 per thread)
// segment bounds in float4 units: x 262144 | Wq 65536 | Wk 1048576 |
// Wv 1048576 | Wo 65536  => total 2490368 (grid 9728 x 256 exactly)
// ===========================================================================
__global__ void cvt_bf16_5(const float* __restrict__ s0, const float* __restrict__ s1,
                           const float* __restrict__ s2, const float* __restrict__ s3,
                           const float* __restrict__ s4,
                           u16* __restrict__ d0, u16* __restrict__ d1,
                           u16* __restrict__ d2, u16* __restrict__ d3,
                           u16* __restrict__ d4)
{
    const int i = blockIdx.x * 256 + threadIdx.x;
    const float* s; u16* d; int base;
    if      (i <  262144) { s = s0; d = d0; base = 0; }
    else if (i <  327680) { s = s1; d = d1; base = 262144; }
    else if (i < 1376256) { s = s2; d = d2; base = 327680; }
    else if (i < 2424832) { s = s3; d = d3; base = 1376256; }
    else                  { s = s4; d = d4; base = 2424832; }
    const int off = (i - base) << 2;
    float4 v = *(const float4*)(s + off);
    ushort4v o = { f2bf(v.x), f2bf(v.y), f2bf(v.z), f2bf(v.w) };
    *(ushort4v*)(d + off) = o;
}

// ===========================================================================
// attention gather: 256 thr = 32 l's x 8 o-groups, grid = B*H*(L/32) = 512
// ===========================================================================
__global__ __launch_bounds__(256) void attn_bf16(
    const u16* __restrict__ qb,     // (B,L,512) bf16
    const u16* __restrict__ kbuf,   // (B,H,K,L,64) bf16
    const u16* __restrict__ vbuf,
    const float* __restrict__ bk,   // (H,K,64) fp32
    const float* __restrict__ bv,
    u16* __restrict__ attnb)        // (B,L,512) bf16
{
    const int tid = threadIdx.x;
    const int j  = tid & 7;          // o-group (8 o's)
    const int ll = tid >> 3;         // 0..31
    const int bid = blockIdx.x;
    const int h = bid & 7;
    const int t = (bid >> 3) & 31;
    const int b = bid >> 8;
    const int l = (t << 5) + ll;
    const int dil = c_dil[h];

    float qf[8];
    {
        ushort8v qv = *(const ushort8v*)(qb + ((size_t)(b * LL + l) * DM) + h * HW + (j << 3));
#pragma unroll
        for (int z = 0; z < 8; ++z) qf[z] = bf2f(qv[z]);
    }

    const size_t bh = ((size_t)b * HH + h) * KT;
    float lg[KT];
#pragma unroll
    for (int k = 0; k < KT; ++k) {
        const int src = l - (KT - 1 - k) * dil;
        float p = 0.f;
        if (src >= 0) {
            ushort8v kv = *(const ushort8v*)(kbuf + ((bh + k) * LL + src) * HW + (j << 3));
#pragma unroll
            for (int z = 0; z < 8; ++z) p += qf[z] * bf2f(kv[z]);
        } else {
            const float* bp = bk + (h * KT + k) * HW + (j << 3);
#pragma unroll
            for (int z = 0; z < 8; ++z) p += qf[z] * bp[z];
        }
        p += __shfl_xor(p, 1);
        p += __shfl_xor(p, 2);
        p += __shfl_xor(p, 4);
        lg[k] = p;
    }

    float m = lg[0];
#pragma unroll
    for (int k = 1; k < KT; ++k) m = fmaxf(m, lg[k]);
    float s = 0.f;
#pragma unroll
    for (int k = 0; k < KT; ++k) { lg[k] = __expf(lg[k] - m); s += lg[k]; }
    const float inv = 1.f / s;

    float acc[8];
#pragma unroll
    for (int z = 0; z < 8; ++z) acc[z] = 0.f;
#pragma unroll
    for (int k = 0; k < KT; ++k) {
        const int src = l - (KT - 1 - k) * dil;
        const float sc = lg[k] * inv;
        if (src >= 0) {
            ushort8v vv = *(const ushort8v*)(vbuf + ((bh + k) * LL + src) * HW + (j << 3));
#pragma unroll
            for (int z = 0; z < 8; ++z) acc[z] = fmaf(sc, bf2f(vv[z]), acc[z]);
        } else {
            const float* bp = bv + (h * KT + k) * HW + (j << 3);
#pragma unroll
            for (int z = 0; z < 8; ++z) acc[z] = fmaf(sc, bp[z], acc[z]);
        }
    }

    ushort8v o;
#pragma unroll
    for (int z = 0; z < 8; ++z) o[z] = f2bf(acc[z] * 0.125f);
    *(ushort8v*)(attnb + (size_t)(b * LL + l) * DM + h * HW + (j << 3)) = o;
}

// ===========================================================================
// ------------------- round-1 fp32 fallback (ws < 91 MB) --------------------
// ===========================================================================
__global__ __launch_bounds__(256, 2) void gemm_nt_bias(
    const float* __restrict__ A, const float* __restrict__ Bm,
    const float* __restrict__ bias, float* __restrict__ C,
    int M, int N, int Kd)
{
    __shared__ float As[16][68];
    __shared__ float Bs[16][68];
    const int tid = threadIdx.x;
    const int tx = tid & 15, ty = tid >> 4;
    const int r0 = blockIdx.y << 6, c0 = blockIdx.x << 6;
    const int lr = tid >> 2, k4 = (tid & 3) << 2;
    const float* Ap = A  + (size_t)(r0 + lr) * Kd + k4;
    const float* Bp = Bm + (size_t)(c0 + lr) * Kd + k4;
    float acc[4][4];
#pragma unroll
    for (int i = 0; i < 4; ++i)
#pragma unroll
        for (int j = 0; j < 4; ++j) acc[i][j] = 0.f;
    for (int d0 = 0; d0 < Kd; d0 += 16) {
        float4 av = *(const float4*)(Ap + d0);
        float4 bv = *(const float4*)(Bp + d0);
        As[k4 + 0][lr] = av.x; As[k4 + 1][lr] = av.y;
        As[k4 + 2][lr] = av.z; As[k4 + 3][lr] = av.w;
        Bs[k4 + 0][lr] = bv.x; Bs[k4 + 1][lr] = bv.y;
        Bs[k4 + 2][lr] = bv.z; Bs[k4 + 3][lr] = bv.w;
        __syncthreads();
#pragma unroll
        for (int dd = 0; dd < 16; ++dd) {
            float4 a4 = *(const float4*)&As[dd][ty << 2];
            float4 b4 = *(const float4*)&Bs[dd][tx << 2];
            float ar[4] = {a4.x, a4.y, a4.z, a4.w};
            float br[4] = {b4.x, b4.y, b4.z, b4.w};
#pragma unroll
            for (int i = 0; i < 4; ++i)
#pragma unroll
                for (int j = 0; j < 4; ++j)
                    acc[i][j] = fmaf(ar[i], br[j], acc[i][j]);
        }
        __syncthreads();
    }
#pragma unroll
    for (int i = 0; i < 4; ++i) {
        float4 o;
        const int c = c0 + (tx << 2);
        o.x = acc[i][0] + bias[c + 0];
        o.y = acc[i][1] + bias[c + 1];
        o.z = acc[i][2] + bias[c + 2];
        o.w = acc[i][3] + bias[c + 3];
        *(float4*)&C[(size_t)(r0 + (ty << 2) + i) * N + c] = o;
    }
}

__device__ __forceinline__ void tile_gemm_f32(
    const float* __restrict__ xb, int src, bool ok,
    const float* __restrict__ wrow,
    int lr, int k4, int tx, int ty,
    float (&As)[16][68], float (&Ws)[16][68], float (&acc)[4][4])
{
#pragma unroll
    for (int i = 0; i < 4; ++i)
#pragma unroll
        for (int j = 0; j < 4; ++j) acc[i][j] = 0.f;
    const float* xrow = xb + (size_t)(ok ? src : 0) * DM + k4;
    for (int d0 = 0; d0 < DM; d0 += 16) {
        float4 av = make_float4(0.f, 0.f, 0.f, 0.f);
        if (ok) av = *(const float4*)(xrow + d0);
        float4 wv = *(const float4*)(wrow + d0);
        As[k4 + 0][lr] = av.x; As[k4 + 1][lr] = av.y;
        As[k4 + 2][lr] = av.z; As[k4 + 3][lr] = av.w;
        Ws[k4 + 0][lr] = wv.x; Ws[k4 + 1][lr] = wv.y;
        Ws[k4 + 2][lr] = wv.z; Ws[k4 + 3][lr] = wv.w;
        __syncthreads();
#pragma unroll
        for (int dd = 0; dd < 16; ++dd) {
            float4 a4 = *(const float4*)&As[dd][ty << 2];
            float4 b4 = *(const float4*)&Ws[dd][tx << 2];
            float ar[4] = {a4.x, a4.y, a4.z, a4.w};
            float br[4] = {b4.x, b4.y, b4.z, b4.w};
#pragma unroll
            for (int i = 0; i < 4; ++i)
#pragma unroll
                for (int j = 0; j < 4; ++j)
                    acc[i][j] = fmaf(ar[i], br[j], acc[i][j]);
        }
        __syncthreads();
    }
}

__global__ __launch_bounds__(256, 2) void attn_kernel(
    const float* __restrict__ x, const float* __restrict__ q,
    const float* __restrict__ Wk, const float* __restrict__ bk,
    const float* __restrict__ Wv, const float* __restrict__ bv,
    float* __restrict__ attn)
{
    __shared__ float As[16][68];
    __shared__ float Ws[16][68];
    __shared__ float qs[64][68];
    __shared__ float lg[64][17];
    __shared__ float red[64][17];
    const int tid = threadIdx.x;
    const int tx = tid & 15, ty = tid >> 4;
    const int bid = blockIdx.x;
    const int h = bid & 7, t = (bid >> 3) & 15, b = bid >> 7;
    const int l0 = t << 6;
    const int dil = c_dil[h];
    const int lr = tid >> 2, k4 = (tid & 3) << 2;
    for (int i = tid; i < 64 * 16; i += 256) {
        int l = i >> 4, o4 = (i & 15) << 2;
        float4 v = *(const float4*)&q[((size_t)(b * LL + l0 + l) * HH + h) * HW + o4];
        *(float4*)&qs[l][o4] = v;
    }
    const float* xb  = x  + (size_t)b * LL * DM;
    const float* Wkh = Wk + (size_t)h * KT * HW * DM;
    const float* Wvh = Wv + (size_t)h * KT * HW * DM;
    const float* bkh = bk + h * KT * HW;
    const float* bvh = bv + h * KT * HW;
    float acc[4][4];
    for (int kk = 0; kk < KT; ++kk) {
        const int src = l0 + lr - (KT - 1 - kk) * dil;
        const bool ok = (src >= 0) && (src < LL);
        tile_gemm_f32(xb, src, ok, Wkh + (size_t)(kk * HW + lr) * DM + k4,
                      lr, k4, tx, ty, As, Ws, acc);
        const float* bkp = bkh + kk * HW + (tx << 2);
#pragma unroll
        for (int i = 0; i < 4; ++i) {
            float p = 0.f;
#pragma unroll
            for (int j = 0; j < 4; ++j)
                p += (acc[i][j] + bkp[j]) * qs[(ty << 2) + i][(tx << 2) + j];
            red[(ty << 2) + i][tx] = p;
        }
        __syncthreads();
        if (tid < 64) {
            float s = 0.f;
#pragma unroll
            for (int u = 0; u < 16; ++u) s += red[tid][u];
            lg[tid][kk] = s;
        }
        __syncthreads();
    }
    if (tid < 64) {
        float m = lg[tid][0];
#pragma unroll
        for (int u = 1; u < KT; ++u) m = fmaxf(m, lg[tid][u]);
        float s = 0.f;
#pragma unroll
        for (int u = 0; u < KT; ++u) {
            float e = expf(lg[tid][u] - m);
            lg[tid][u] = e; s += e;
        }
        float inv = 1.f / s;
#pragma unroll
        for (int u = 0; u < KT; ++u) lg[tid][u] *= inv;
    }
    __syncthreads();
    float vacc[4][4];
#pragma unroll
    for (int i = 0; i < 4; ++i)
#pragma unroll
        for (int j = 0; j < 4; ++j) vacc[i][j] = 0.f;
    for (int kk = 0; kk < KT; ++kk) {
        const int src = l0 + lr - (KT - 1 - kk) * dil;
        const bool ok = (src >= 0) && (src < LL);
        tile_gemm_f32(xb, src, ok, Wvh + (size_t)(kk * HW + lr) * DM + k4,
                      lr, k4, tx, ty, As, Ws, acc);
        const float* bvp = bvh + kk * HW + (tx << 2);
#pragma unroll
        for (int i = 0; i < 4; ++i) {
            float sc = lg[(ty << 2) + i][kk];
#pragma unroll
            for (int j = 0; j < 4; ++j)
                vacc[i][j] = fmaf(sc, acc[i][j] + bvp[j], vacc[i][j]);
        }
    }
#pragma unroll
    for (int i = 0; i < 4; ++i) {
        float4 o;
        o.x = vacc[i][0] * 0.125f;
        o.y = vacc[i][1] * 0.125f;
        o.z = vacc[i][2] * 0.125f;
        o.w = vacc[i][3] * 0.125f;
        *(float4*)&attn[((size_t)(b * LL + l0 + (ty << 2) + i) * HH + h) * HW + (tx << 2)] = o;
    }
}

// ===========================================================================
extern "C" void kernel_launch(void* const* d_in, const int* in_sizes, int n_in,
                              void* d_out, int out_size, void* d_ws, size_t ws_size,
                              hipStream_t stream)
{
    const float* x  = (const float*)d_in[0];
    const float* Wq = (const float*)d_in[1];
    const float* bq = (const float*)d_in[2];
    const float* Wk = (const float*)d_in[3];
    const float* bk = (const float*)d_in[4];
    const float* Wv = (const float*)d_in[5];
    const float* bv = (const float*)d_in[6];
    const float* Wo = (const float*)d_in[7];
    const float* bo = (const float*)d_in[8];
    float* out = (float*)d_out;

    const int M = BD * LL;  // 2048

    // ws layout (ushort elements) for the fast path
    const size_t N_X   = (size_t)BD * LL * DM;          // 1,048,576
    const size_t N_WQ  = (size_t)HH * HW * DM;          //   262,144
    const size_t N_WK  = (size_t)HH * KT * HW * DM;     // 4,194,304
    const size_t N_KV  = (size_t)BD * HH * KT * LL * HW;// 16,777,216
    const size_t NEED  = (N_X + N_WQ + 2 * N_WK + N_WQ + 2 * N_X + 2 * N_KV) * 2;

    if (ws_size >= NEED) {
        u16* xb    = (u16*)d_ws;
        u16* wqb   = xb   + N_X;
        u16* wkb   = wqb  + N_WQ;      // wkb/wvb adjacent: one 16384x512 B matrix
        u16* wvb   = wkb  + N_WK;
        u16* wob   = wvb  + N_WK;
        u16* qb    = wob  + N_WQ;
        u16* attnb = qb   + N_X;
        u16* kbuf  = attnb + N_X;
        u16* vbuf  = kbuf + N_KV;

        cvt_bf16_5<<<9728, 256, 0, stream>>>(x, Wq, Wk, Wv, Wo,
                                             xb, wqb, wkb, wvb, wob);

        // q = x * Wq^T + bq  -> bf16 (B,L,512)
        gemm_bf16<<<dim3(4, 16), 256, 0, stream>>>(
            xb, wqb, M, HH * HW, DM, bq, nullptr, qb, nullptr, 1);

        // k/v = x * [Wk;Wv]^T + bk/bv -> bf16 scattered (B,H,K,L,64)
        gemm_bf16<<<dim3(128, 16), 256, 0, stream>>>(
            xb, wkb, M, 2 * HH * KT * HW, DM, bk, bv, kbuf, vbuf, 2);

        // gather + softmax + weighted sum -> bf16 (B,L,512)
        attn_bf16<<<BD * HH * (LL / 32), 256, 0, stream>>>(
            qb, kbuf, vbuf, bk, bv, attnb);

        // out = attn * Wo^T + bo -> fp32
        gemm_bf16<<<dim3(4, 16), 256, 0, stream>>>(
            attnb, wob, M, DM, HH * HW, bo, nullptr, out, nullptr, 0);
    } else {
        // fp32 fallback (round-1 path, 8 MB ws)
        float* qws = (float*)d_ws;
        float* aws = qws + (size_t)BD * LL * HH * HW;
        gemm_nt_bias<<<dim3((HH * HW) / 64, M / 64), 256, 0, stream>>>(
            x, Wq, bq, qws, M, HH * HW, DM);
        attn_kernel<<<BD * HH * (LL / 64), 256, 0, stream>>>(
            x, qws, Wk, bk, Wv, bv, aws);
        gemm_nt_bias<<<dim3(DM / 64, M / 64), 256, 0, stream>>>(
            aws, Wo, bo, out, M, DM, HH * HW);
    }
}

// Round 3
// 205.841 us; speedup vs baseline: 5.0274x; 1.0284x over previous
//
#include <hip/hip_runtime.h>

// LCSA: dilated local-window self-attention.
// B=2, L=1024, D=512, H=8, HEAD_W=64, KERNEL=16, dilations {1,1,2,2,4,4,8,8},
// MODE=forward -> src(l,k) = l - (15-k)*dil, zero-padded outside [0,L).
//
// R3 fast path:
//   cvt_swz:  fp32->bf16 + per-row XOR chunk swizzle for x, [Wq|Wk|Wv], Wo
//             (swizzle kills the 8-way LDS bank conflicts in the GEMM:
//              stored[r][kb*32+c*8+j] = orig[r][kb*32+(c^((r>>1)&3))*8+j])
//   gemm_bf16 mode2: [q|k|v] = x*[Wq|Wk|Wv]^T + bias, N=16896 one dispatch;
//             q -> row-major bf16, k/v -> scattered (B,H,K,L,64) bf16
//   attn_bf16: gather + softmax + weighted sum; writes attnb SWIZZLED
//   gemm_bf16 mode0: out = attn*Wo^T + bo (fp32)
// Fallback: round-1 fp32 path (8 MB ws).

#define BD 2
#define LL 1024
#define DM 512
#define HH 8
#define KT 16
#define HW 64

typedef unsigned short u16;
typedef unsigned int u32;
typedef __bf16 bf16x8 __attribute__((ext_vector_type(8)));
typedef float f32x4 __attribute__((ext_vector_type(4)));
typedef unsigned short ushort8v __attribute__((ext_vector_type(8)));

__constant__ int c_dil[8] = {1, 1, 2, 2, 4, 4, 8, 8};

__device__ __forceinline__ float bf2f(u16 u) {
    return __builtin_bit_cast(float, (u32)u << 16);
}
__device__ __forceinline__ u16 f2bf(float f) {   // round-to-nearest-even
    u32 u = __builtin_bit_cast(u32, f);
    return (u16)((u + 0x7fffu + ((u >> 16) & 1u)) >> 16);
}

// async global->LDS, 16 B per lane; lds dest must be (uniform base + lane*16)
__device__ __forceinline__ void gl_lds16(const u16* g, u16* l) {
    __builtin_amdgcn_global_load_lds(
        (__attribute__((address_space(1))) void*)g,
        (__attribute__((address_space(3))) void*)l, 16, 0, 0);
}

// ===========================================================================
// bf16 NT GEMM, 128x128 tile, BK=32, 256 thr (4 waves, 64x64 each),
// 16x16x32 MFMA. A and B stored SWIZZLED (see cvt_swz). K fixed = 512.
// mode 0: C0 fp32 row-major (stride N) + bias0
// mode 2: col <  512          -> qb  (C0, bf16 row-major stride 512, +bias0)
//         col in [512, 8704)  -> kbuf(C1, (B,H,K,L,64) scatter, +bias1)
//         col >= 8704         -> vbuf(C2, same scatter, +bias2)
// ===========================================================================
__global__ __launch_bounds__(256, 4) void gemm_bf16(
    const u16* __restrict__ A, const u16* __restrict__ Bm,
    int N,
    const float* __restrict__ bias0, const float* __restrict__ bias1,
    const float* __restrict__ bias2,
    void* __restrict__ C0, void* __restrict__ C1, void* __restrict__ C2,
    int mode)
{
    __shared__ u16 As[128 * 32];
    __shared__ u16 Bs[128 * 32];

    const int tid  = threadIdx.x;
    const int wave = tid >> 6, lane = tid & 63;
    const int m0 = blockIdx.y << 7, n0 = blockIdx.x << 7;
    const int r0 = tid >> 2;            // staging row 0..63 (round 0)
    const int cc = (tid & 3) << 3;      // staging k-offset (elements)
    const int mw = (wave >> 1) << 6;    // wave's 64x64 sub-tile
    const int nw = (wave & 1) << 6;
    const int lr = lane & 15;           // frag row/col within 16
    const int qg = lane >> 4;           // k-quarter
    // swizzled chunk offset: stored chunk (qg ^ s(row)), s(row)=(row>>1)&3,
    // row = 16-aligned base + lr  =>  s depends on lr only.
    const int ksw = ((qg ^ ((lr >> 1) & 3)) << 3);

    const u16* Ag = A  + (size_t)(m0 + r0) * DM + cc;
    const u16* Bg = Bm + (size_t)(n0 + r0) * DM + cc;
    u16* lA = &As[0] + tid * 8;         // byte offset = wave*1024 + lane*16
    u16* lB = &Bs[0] + tid * 8;

    f32x4 acc[4][4];
#pragma unroll
    for (int i = 0; i < 4; ++i)
#pragma unroll
        for (int j = 0; j < 4; ++j) acc[i][j] = (f32x4){0.f, 0.f, 0.f, 0.f};

    for (int k0 = 0; k0 < DM; k0 += 32) {
        gl_lds16(Ag + k0, lA);
        gl_lds16(Ag + k0 + (size_t)64 * DM, lA + 64 * 32);
        gl_lds16(Bg + k0, lB);
        gl_lds16(Bg + k0 + (size_t)64 * DM, lB + 64 * 32);
        __syncthreads();

        bf16x8 af[4], bfr[4];
#pragma unroll
        for (int i = 0; i < 4; ++i)
            af[i] = *(const bf16x8*)&As[(mw + (i << 4) + lr) * 32 + ksw];
#pragma unroll
        for (int j = 0; j < 4; ++j)
            bfr[j] = *(const bf16x8*)&Bs[(nw + (j << 4) + lr) * 32 + ksw];
#pragma unroll
        for (int i = 0; i < 4; ++i)
#pragma unroll
            for (int j = 0; j < 4; ++j)
                acc[i][j] = __builtin_amdgcn_mfma_f32_16x16x32_bf16(
                    af[i], bfr[j], acc[i][j], 0, 0, 0);
        __syncthreads();
    }

    // epilogue: row = m0+mw+16i+(lane>>4)*4+r, col = n0+nw+16j+(lane&15)
#pragma unroll
    for (int i = 0; i < 4; ++i) {
        const int rowb = m0 + mw + (i << 4) + (qg << 2);
#pragma unroll
        for (int j = 0; j < 4; ++j) {
            const int col = n0 + nw + (j << 4) + lr;
#pragma unroll
            for (int r = 0; r < 4; ++r) {
                const float v = acc[i][j][r];
                const int row = rowb + r;
                if (mode == 0) {
                    ((float*)C0)[(size_t)row * N + col] = v + bias0[col];
                } else {
                    const int b = row >> 10, l = row & 1023;
                    if (col < 512) {
                        ((u16*)C0)[(size_t)row * 512 + col] = f2bf(v + bias0[col]);
                    } else if (col < 8704) {
                        const int nl = col - 512;
                        const size_t off =
                            ((((size_t)b * HH + (nl >> 10)) * KT + ((nl >> 6) & 15)) * LL + l) * HW
                            + (nl & 63);
                        ((u16*)C1)[off] = f2bf(v + bias1[nl]);
                    } else {
                        const int nl = col - 8704;
                        const size_t off =
                            ((((size_t)b * HH + (nl >> 10)) * KT + ((nl >> 6) & 15)) * LL + l) * HW
                            + (nl & 63);
                        ((u16*)C2)[off] = f2bf(v + bias2[nl]);
                    }
                }
            }
        }
    }
}

// ===========================================================================
// fp32 -> bf16 + swizzle. One thread per 16-B output chunk; writes are fully
// coalesced, reads gather 32-B spans (4 lanes share each 128-B line).
// Segments (chunks = rows*64): x 131072 | [Wq|Wk|Wv] 1081344 | Wo 32768.
// Total 1245184 chunks = 4864 blocks x 256.
// ===========================================================================
__global__ void cvt_swz(const float* __restrict__ x,  const float* __restrict__ Wq,
                        const float* __restrict__ Wk, const float* __restrict__ Wv,
                        const float* __restrict__ Wo,
                        u16* __restrict__ xb, u16* __restrict__ wb,
                        u16* __restrict__ wob)
{
    const int i = blockIdx.x * 256 + threadIdx.x;
    const float* src; u16* dst; int row, c;
    if (i < 131072) {
        row = i >> 6; c = i & 63;
        src = x + (size_t)row * DM;
        dst = xb + (size_t)row * DM;
    } else if (i < 131072 + 1081344) {
        const int t = i - 131072;
        row = t >> 6; c = t & 63;
        if      (row <  512) src = Wq + (size_t)row * DM;
        else if (row < 8704) src = Wk + (size_t)(row - 512) * DM;
        else                 src = Wv + (size_t)(row - 8704) * DM;
        dst = wb + (size_t)row * DM;
    } else {
        const int t = i - 1212416;
        row = t >> 6; c = t & 63;
        src = Wo + (size_t)row * DM;
        dst = wob + (size_t)row * DM;
    }
    const int kb = c >> 2, cc = c & 3, s = (row >> 1) & 3;
    const float* p = src + kb * 32 + ((cc ^ s) << 3);   // orig chunk cc^s
    ushort8v o;
#pragma unroll
    for (int z = 0; z < 8; ++z) o[z] = f2bf(p[z]);
    *(ushort8v*)(dst + kb * 32 + (cc << 3)) = o;        // stored chunk cc
}

// ===========================================================================
// attention gather: 256 thr = 32 l's x 8 o-groups, grid = B*H*(L/32) = 512.
// Writes attnb SWIZZLED (it is the A matrix of the out-projection GEMM).
// ===========================================================================
__global__ __launch_bounds__(256) void attn_bf16(
    const u16* __restrict__ qb,     // (B,L,512) bf16 row-major
    const u16* __restrict__ kbuf,   // (B,H,K,L,64) bf16
    const u16* __restrict__ vbuf,
    const float* __restrict__ bk,   // (H,K,64) fp32
    const float* __restrict__ bv,
    u16* __restrict__ attnb)        // (B,L,512) bf16 swizzled
{
    const int tid = threadIdx.x;
    const int j  = tid & 7;          // o-group (8 o's)
    const int ll = tid >> 3;         // 0..31
    const int bid = blockIdx.x;
    const int h = bid & 7;
    const int t = (bid >> 3) & 31;
    const int b = bid >> 8;
    const int l = (t << 5) + ll;
    const int dil = c_dil[h];

    float qf[8];
    {
        ushort8v qv = *(const ushort8v*)(qb + ((size_t)(b * LL + l) * DM) + h * HW + (j << 3));
#pragma unroll
        for (int z = 0; z < 8; ++z) qf[z] = bf2f(qv[z]);
    }

    const size_t bh = ((size_t)b * HH + h) * KT;
    float lg[KT];
#pragma unroll
    for (int k = 0; k < KT; ++k) {
        const int src = l - (KT - 1 - k) * dil;
        float p = 0.f;
        if (src >= 0) {
            ushort8v kv = *(const ushort8v*)(kbuf + ((bh + k) * LL + src) * HW + (j << 3));
#pragma unroll
            for (int z = 0; z < 8; ++z) p += qf[z] * bf2f(kv[z]);
        } else {
            const float* bp = bk + (h * KT + k) * HW + (j << 3);
#pragma unroll
            for (int z = 0; z < 8; ++z) p += qf[z] * bp[z];
        }
        p += __shfl_xor(p, 1);
        p += __shfl_xor(p, 2);
        p += __shfl_xor(p, 4);
        lg[k] = p;
    }

    float m = lg[0];
#pragma unroll
    for (int k = 1; k < KT; ++k) m = fmaxf(m, lg[k]);
    float s = 0.f;
#pragma unroll
    for (int k = 0; k < KT; ++k) { lg[k] = __expf(lg[k] - m); s += lg[k]; }
    const float inv = 1.f / s;

    float acc[8];
#pragma unroll
    for (int z = 0; z < 8; ++z) acc[z] = 0.f;
#pragma unroll
    for (int k = 0; k < KT; ++k) {
        const int src = l - (KT - 1 - k) * dil;
        const float sc = lg[k] * inv;
        if (src >= 0) {
            ushort8v vv = *(const ushort8v*)(vbuf + ((bh + k) * LL + src) * HW + (j << 3));
#pragma unroll
            for (int z = 0; z < 8; ++z) acc[z] = fmaf(sc, bf2f(vv[z]), acc[z]);
        } else {
            const float* bp = bv + (h * KT + k) * HW + (j << 3);
#pragma unroll
            for (int z = 0; z < 8; ++z) acc[z] = fmaf(sc, bp[z], acc[z]);
        }
    }

    ushort8v o;
#pragma unroll
    for (int z = 0; z < 8; ++z) o[z] = f2bf(acc[z] * 0.125f);
    // swizzled store: orig 8-chunk index k8 = h*8+j goes to stored chunk
    // (k8&3)^s within its 32-block, s = (row>>1)&3 = (l>>1)&3
    const int row = b * LL + l;
    const int k8 = h * 8 + j;
    const int sw = ((k8 & 3) ^ ((l >> 1) & 3)) << 3;
    *(ushort8v*)(attnb + (size_t)row * DM + ((k8 >> 2) << 5) + sw) = o;
}

// ===========================================================================
// ------------------- round-1 fp32 fallback (small ws) ----------------------
// ===========================================================================
__global__ __launch_bounds__(256, 2) void gemm_nt_bias(
    const float* __restrict__ A, const float* __restrict__ Bm,
    const float* __restrict__ bias, float* __restrict__ C,
    int M, int N, int Kd)
{
    __shared__ float As[16][68];
    __shared__ float Bs[16][68];
    const int tid = threadIdx.x;
    const int tx = tid & 15, ty = tid >> 4;
    const int r0 = blockIdx.y << 6, c0 = blockIdx.x << 6;
    const int lr = tid >> 2, k4 = (tid & 3) << 2;
    const float* Ap = A  + (size_t)(r0 + lr) * Kd + k4;
    const float* Bp = Bm + (size_t)(c0 + lr) * Kd + k4;
    float acc[4][4];
#pragma unroll
    for (int i = 0; i < 4; ++i)
#pragma unroll
        for (int j = 0; j < 4; ++j) acc[i][j] = 0.f;
    for (int d0 = 0; d0 < Kd; d0 += 16) {
        float4 av = *(const float4*)(Ap + d0);
        float4 bv = *(const float4*)(Bp + d0);
        As[k4 + 0][lr] = av.x; As[k4 + 1][lr] = av.y;
        As[k4 + 2][lr] = av.z; As[k4 + 3][lr] = av.w;
        Bs[k4 + 0][lr] = bv.x; Bs[k4 + 1][lr] = bv.y;
        Bs[k4 + 2][lr] = bv.z; Bs[k4 + 3][lr] = bv.w;
        __syncthreads();
#pragma unroll
        for (int dd = 0; dd < 16; ++dd) {
            float4 a4 = *(const float4*)&As[dd][ty << 2];
            float4 b4 = *(const float4*)&Bs[dd][tx << 2];
            float ar[4] = {a4.x, a4.y, a4.z, a4.w};
            float br[4] = {b4.x, b4.y, b4.z, b4.w};
#pragma unroll
            for (int i = 0; i < 4; ++i)
#pragma unroll
                for (int j = 0; j < 4; ++j)
                    acc[i][j] = fmaf(ar[i], br[j], acc[i][j]);
        }
        __syncthreads();
    }
#pragma unroll
    for (int i = 0; i < 4; ++i) {
        float4 o;
        const int c = c0 + (tx << 2);
        o.x = acc[i][0] + bias[c + 0];
        o.y = acc[i][1] + bias[c + 1];
        o.z = acc[i][2] + bias[c + 2];
        o.w = acc[i][3] + bias[c + 3];
        *(float4*)&C[(size_t)(r0 + (ty << 2) + i) * N + c] = o;
    }
}

__device__ __forceinline__ void tile_gemm_f32(
    const float* __restrict__ xb, int src, bool ok,
    const float* __restrict__ wrow,
    int lr, int k4, int tx, int ty,
    float (&As)[16][68], float (&Ws)[16][68], float (&acc)[4][4])
{
#pragma unroll
    for (int i = 0; i < 4; ++i)
#pragma unroll
        for (int j = 0; j < 4; ++j) acc[i][j] = 0.f;
    const float* xrow = xb + (size_t)(ok ? src : 0) * DM + k4;
    for (int d0 = 0; d0 < DM; d0 += 16) {
        float4 av = make_float4(0.f, 0.f, 0.f, 0.f);
        if (ok) av = *(const float4*)(xrow + d0);
        float4 wv = *(const float4*)(wrow + d0);
        As[k4 + 0][lr] = av.x; As[k4 + 1][lr] = av.y;
        As[k4 + 2][lr] = av.z; As[k4 + 3][lr] = av.w;
        Ws[k4 + 0][lr] = wv.x; Ws[k4 + 1][lr] = wv.y;
        Ws[k4 + 2][lr] = wv.z; Ws[k4 + 3][lr] = wv.w;
        __syncthreads();
#pragma unroll
        for (int dd = 0; dd < 16; ++dd) {
            float4 a4 = *(const float4*)&As[dd][ty << 2];
            float4 b4 = *(const float4*)&Ws[dd][tx << 2];
            float ar[4] = {a4.x, a4.y, a4.z, a4.w};
            float br[4] = {b4.x, b4.y, b4.z, b4.w};
#pragma unroll
            for (int i = 0; i < 4; ++i)
#pragma unroll
                for (int j = 0; j < 4; ++j)
                    acc[i][j] = fmaf(ar[i], br[j], acc[i][j]);
        }
        __syncthreads();
    }
}

__global__ __launch_bounds__(256, 2) void attn_kernel(
    const float* __restrict__ x, const float* __restrict__ q,
    const float* __restrict__ Wk, const float* __restrict__ bk,
    const float* __restrict__ Wv, const float* __restrict__ bv,
    float* __restrict__ attn)
{
    __shared__ float As[16][68];
    __shared__ float Ws[16][68];
    __shared__ float qs[64][68];
    __shared__ float lg[64][17];
    __shared__ float red[64][17];
    const int tid = threadIdx.x;
    const int tx = tid & 15, ty = tid >> 4;
    const int bid = blockIdx.x;
    const int h = bid & 7, t = (bid >> 3) & 15, b = bid >> 7;
    const int l0 = t << 6;
    const int dil = c_dil[h];
    const int lr = tid >> 2, k4 = (tid & 3) << 2;
    for (int i = tid; i < 64 * 16; i += 256) {
        int l = i >> 4, o4 = (i & 15) << 2;
        float4 v = *(const float4*)&q[((size_t)(b * LL + l0 + l) * HH + h) * HW + o4];
        *(float4*)&qs[l][o4] = v;
    }
    const float* xb  = x  + (size_t)b * LL * DM;
    const float* Wkh = Wk + (size_t)h * KT * HW * DM;
    const float* Wvh = Wv + (size_t)h * KT * HW * DM;
    const float* bkh = bk + h * KT * HW;
    const float* bvh = bv + h * KT * HW;
    float acc[4][4];
    for (int kk = 0; kk < KT; ++kk) {
        const int src = l0 + lr - (KT - 1 - kk) * dil;
        const bool ok = (src >= 0) && (src < LL);
        tile_gemm_f32(xb, src, ok, Wkh + (size_t)(kk * HW + lr) * DM + k4,
                      lr, k4, tx, ty, As, Ws, acc);
        const float* bkp = bkh + kk * HW + (tx << 2);
#pragma unroll
        for (int i = 0; i < 4; ++i) {
            float p = 0.f;
#pragma unroll
            for (int j = 0; j < 4; ++j)
                p += (acc[i][j] + bkp[j]) * qs[(ty << 2) + i][(tx << 2) + j];
            red[(ty << 2) + i][tx] = p;
        }
        __syncthreads();
        if (tid < 64) {
            float s = 0.f;
#pragma unroll
            for (int u = 0; u < 16; ++u) s += red[tid][u];
            lg[tid][kk] = s;
        }
        __syncthreads();
    }
    if (tid < 64) {
        float m = lg[tid][0];
#pragma unroll
        for (int u = 1; u < KT; ++u) m = fmaxf(m, lg[tid][u]);
        float s = 0.f;
#pragma unroll
        for (int u = 0; u < KT; ++u) {
            float e = expf(lg[tid][u] - m);
            lg[tid][u] = e; s += e;
        }
        float inv = 1.f / s;
#pragma unroll
        for (int u = 0; u < KT; ++u) lg[tid][u] *= inv;
    }
    __syncthreads();
    float vacc[4][4];
#pragma unroll
    for (int i = 0; i < 4; ++i)
#pragma unroll
        for (int j = 0; j < 4; ++j) vacc[i][j] = 0.f;
    for (int kk = 0; kk < KT; ++kk) {
        const int src = l0 + lr - (KT - 1 - kk) * dil;
        const bool ok = (src >= 0) && (src < LL);
        tile_gemm_f32(xb, src, ok, Wvh + (size_t)(kk * HW + lr) * DM + k4,
                      lr, k4, tx, ty, As, Ws, acc);
        const float* bvp = bvh + kk * HW + (tx << 2);
#pragma unroll
        for (int i = 0; i < 4; ++i) {
            float sc = lg[(ty << 2) + i][kk];
#pragma unroll
            for (int j = 0; j < 4; ++j)
                vacc[i][j] = fmaf(sc, acc[i][j] + bvp[j], vacc[i][j]);
        }
    }
#pragma unroll
    for (int i = 0; i < 4; ++i) {
        float4 o;
        o.x = vacc[i][0] * 0.125f;
        o.y = vacc[i][1] * 0.125f;
        o.z = vacc[i][2] * 0.125f;
        o.w = vacc[i][3] * 0.125f;
        *(float4*)&attn[((size_t)(b * LL + l0 + (ty << 2) + i) * HH + h) * HW + (tx << 2)] = o;
    }
}

// ===========================================================================
extern "C" void kernel_launch(void* const* d_in, const int* in_sizes, int n_in,
                              void* d_out, int out_size, void* d_ws, size_t ws_size,
                              hipStream_t stream)
{
    const float* x  = (const float*)d_in[0];
    const float* Wq = (const float*)d_in[1];
    const float* bq = (const float*)d_in[2];
    const float* Wk = (const float*)d_in[3];
    const float* bk = (const float*)d_in[4];
    const float* Wv = (const float*)d_in[5];
    const float* bv = (const float*)d_in[6];
    const float* Wo = (const float*)d_in[7];
    const float* bo = (const float*)d_in[8];
    float* out = (float*)d_out;

    const int M = BD * LL;  // 2048

    // ws layout (ushort elements) for the fast path
    const size_t N_X   = (size_t)BD * LL * DM;            // 1,048,576
    const size_t N_WB  = (size_t)(512 + 2 * HH * KT * HW) * DM; // 8,650,752
    const size_t N_WO  = (size_t)DM * DM;                 //   262,144
    const size_t N_KV  = (size_t)BD * HH * KT * LL * HW;  // 16,777,216
    const size_t NEED  = (N_X + N_WB + N_WO + 2 * N_X + 2 * N_KV) * 2;

    if (ws_size >= NEED) {
        u16* xb    = (u16*)d_ws;
        u16* wb    = xb    + N_X;      // [Wq|Wk|Wv] swizzled, 16896 x 512
        u16* wob   = wb    + N_WB;
        u16* qb    = wob   + N_WO;
        u16* attnb = qb    + N_X;
        u16* kbuf  = attnb + N_X;
        u16* vbuf  = kbuf  + N_KV;

        cvt_swz<<<4864, 256, 0, stream>>>(x, Wq, Wk, Wv, Wo, xb, wb, wob);

        // [q|k|v] = x * [Wq|Wk|Wv]^T + bias  (N = 16896)
        gemm_bf16<<<dim3(132, 16), 256, 0, stream>>>(
            xb, wb, 16896, bq, bk, bv, qb, kbuf, vbuf, 2);

        // gather + softmax + weighted sum -> attnb (swizzled)
        attn_bf16<<<BD * HH * (LL / 32), 256, 0, stream>>>(
            qb, kbuf, vbuf, bk, bv, attnb);

        // out = attn * Wo^T + bo -> fp32
        gemm_bf16<<<dim3(4, 16), 256, 0, stream>>>(
            attnb, wob, DM, bo, nullptr, nullptr, out, nullptr, nullptr, 0);
    } else {
        // fp32 fallback (round-1 path, 8 MB ws)
        float* qws = (float*)d_ws;
        float* aws = qws + (size_t)BD * LL * HH * HW;
        gemm_nt_bias<<<dim3((HH * HW) / 64, M / 64), 256, 0, stream>>>(
            x, Wq, bq, qws, M, HH * HW, DM);
        attn_kernel<<<BD * HH * (LL / 64), 256, 0, stream>>>(
            x, qws, Wk, bk, Wv, bv, aws);
        gemm_nt_bias<<<dim3(DM / 64, M / 64), 256, 0, stream>>>(
            aws, Wo, bo, out, M, DM, HH * HW);
    }
}

// Round 4
// 204.972 us; speedup vs baseline: 5.0487x; 1.0042x over previous
//
#include <hip/hip_runtime.h>

// LCSA: dilated local-window self-attention.
// B=2, L=1024, D=512, H=8, HEAD_W=64, KERNEL=16, dilations {1,1,2,2,4,4,8,8},
// MODE=forward -> src(l,k) = l - (15-k)*dil, zero-padded outside [0,L).
//
// R4 fast path:
//   cvt_swz:  fp32->bf16 + per-row XOR chunk swizzle (coalesced both sides):
//             stored[r][kb*32+c*8+j] = orig[r][kb*32+(c^((r>>1)&3))*8+j]
//   gemm_bf16 mode2: [q|k|v] = x*[Wq|Wk|Wv]^T + bias, N padded 16896->17408
//             (136 n-tiles = 8 XCDs x 17); 1-D grid 2176 with explicit
//             XCD-pinned mapping: xcd=bid&7, nt=xcd*17+(bid>>7), mt=(bid>>3)&15
//             -> each XCD keeps 17 B-tiles (2.2MB) + A (2MB) in its 4MB L2.
//             q -> row-major bf16, k/v -> scattered (B,H,K,L,64), pad skipped.
//   attn_bf16: gather + softmax + weighted sum; writes attnb SWIZZLED
//   gemm_bf16 mode0: out = attn*Wo^T + bo (fp32)
// Fallback: round-1 fp32 path (8 MB ws).

#define BD 2
#define LL 1024
#define DM 512
#define HH 8
#define KT 16
#define HW 64

#define NQKV 16896          // 512 q + 8192 k + 8192 v
#define NPAD 17408          // 136 tiles of 128 (8 XCDs x 17)

typedef unsigned short u16;
typedef unsigned int u32;
typedef __bf16 bf16x8 __attribute__((ext_vector_type(8)));
typedef float f32x4 __attribute__((ext_vector_type(4)));
typedef unsigned short ushort4v __attribute__((ext_vector_type(4)));
typedef unsigned short ushort8v __attribute__((ext_vector_type(8)));

__constant__ int c_dil[8] = {1, 1, 2, 2, 4, 4, 8, 8};

__device__ __forceinline__ float bf2f(u16 u) {
    return __builtin_bit_cast(float, (u32)u << 16);
}
__device__ __forceinline__ u16 f2bf(float f) {   // round-to-nearest-even
    u32 u = __builtin_bit_cast(u32, f);
    return (u16)((u + 0x7fffu + ((u >> 16) & 1u)) >> 16);
}

// async global->LDS, 16 B per lane; lds dest must be (uniform base + lane*16)
__device__ __forceinline__ void gl_lds16(const u16* g, u16* l) {
    __builtin_amdgcn_global_load_lds(
        (__attribute__((address_space(1))) void*)g,
        (__attribute__((address_space(3))) void*)l, 16, 0, 0);
}

// ===========================================================================
// bf16 NT GEMM, 128x128 tile, BK=32, 256 thr (4 waves, 64x64 each),
// 16x16x32 MFMA. A and B stored SWIZZLED (see cvt_swz). K fixed = 512.
// mode 0: 2-D grid; C0 fp32 row-major (stride N) + bias0
// mode 2: 1-D grid 2176, XCD-pinned mapping (see header);
//         col <  512           -> qb  (C0, bf16 row-major stride 512, +bias0)
//         col in [512, 8704)   -> kbuf(C1, (B,H,K,L,64) scatter, +bias1)
//         col in [8704, 16896) -> vbuf(C2, same scatter, +bias2)
//         col >= 16896         -> discarded (padding)
// ===========================================================================
__global__ __launch_bounds__(256, 4) void gemm_bf16(
    const u16* __restrict__ A, const u16* __restrict__ Bm,
    int N,
    const float* __restrict__ bias0, const float* __restrict__ bias1,
    const float* __restrict__ bias2,
    void* __restrict__ C0, void* __restrict__ C1, void* __restrict__ C2,
    int mode)
{
    __shared__ u16 As[128 * 32];
    __shared__ u16 Bs[128 * 32];

    const int tid  = threadIdx.x;
    const int wave = tid >> 6, lane = tid & 63;

    int m0, n0;
    if (mode == 2) {
        const int bid = blockIdx.x;      // 0..2175
        const int xcd = bid & 7;
        const int nt  = xcd * 17 + (bid >> 7);   // (bid>>3)>>4
        const int mt  = (bid >> 3) & 15;
        m0 = mt << 7;
        n0 = nt << 7;
    } else {
        m0 = blockIdx.y << 7;
        n0 = blockIdx.x << 7;
    }

    const int r0 = tid >> 2;            // staging row 0..63 (round 0)
    const int cc = (tid & 3) << 3;      // staging k-offset (elements)
    const int mw = (wave >> 1) << 6;    // wave's 64x64 sub-tile
    const int nw = (wave & 1) << 6;
    const int lr = lane & 15;           // frag row/col within 16
    const int qg = lane >> 4;           // k-quarter
    // swizzled chunk offset: stored chunk (qg ^ s(row)), s(row)=(row>>1)&3
    const int ksw = ((qg ^ ((lr >> 1) & 3)) << 3);

    const u16* Ag = A  + (size_t)(m0 + r0) * DM + cc;
    const u16* Bg = Bm + (size_t)(n0 + r0) * DM + cc;
    u16* lA = &As[0] + tid * 8;         // byte offset = wave*1024 + lane*16
    u16* lB = &Bs[0] + tid * 8;

    f32x4 acc[4][4];
#pragma unroll
    for (int i = 0; i < 4; ++i)
#pragma unroll
        for (int j = 0; j < 4; ++j) acc[i][j] = (f32x4){0.f, 0.f, 0.f, 0.f};

    for (int k0 = 0; k0 < DM; k0 += 32) {
        gl_lds16(Ag + k0, lA);
        gl_lds16(Ag + k0 + (size_t)64 * DM, lA + 64 * 32);
        gl_lds16(Bg + k0, lB);
        gl_lds16(Bg + k0 + (size_t)64 * DM, lB + 64 * 32);
        __syncthreads();

        bf16x8 af[4], bfr[4];
#pragma unroll
        for (int i = 0; i < 4; ++i)
            af[i] = *(const bf16x8*)&As[(mw + (i << 4) + lr) * 32 + ksw];
#pragma unroll
        for (int j = 0; j < 4; ++j)
            bfr[j] = *(const bf16x8*)&Bs[(nw + (j << 4) + lr) * 32 + ksw];
#pragma unroll
        for (int i = 0; i < 4; ++i)
#pragma unroll
            for (int j = 0; j < 4; ++j)
                acc[i][j] = __builtin_amdgcn_mfma_f32_16x16x32_bf16(
                    af[i], bfr[j], acc[i][j], 0, 0, 0);
        __syncthreads();
    }

    // epilogue: row = m0+mw+16i+(lane>>4)*4+r, col = n0+nw+16j+(lane&15)
#pragma unroll
    for (int i = 0; i < 4; ++i) {
        const int rowb = m0 + mw + (i << 4) + (qg << 2);
#pragma unroll
        for (int j = 0; j < 4; ++j) {
            const int col = n0 + nw + (j << 4) + lr;
#pragma unroll
            for (int r = 0; r < 4; ++r) {
                const float v = acc[i][j][r];
                const int row = rowb + r;
                if (mode == 0) {
                    ((float*)C0)[(size_t)row * N + col] = v + bias0[col];
                } else {
                    const int b = row >> 10, l = row & 1023;
                    if (col < 512) {
                        ((u16*)C0)[(size_t)row * 512 + col] = f2bf(v + bias0[col]);
                    } else if (col < 8704) {
                        const int nl = col - 512;
                        const size_t off =
                            ((((size_t)b * HH + (nl >> 10)) * KT + ((nl >> 6) & 15)) * LL + l) * HW
                            + (nl & 63);
                        ((u16*)C1)[off] = f2bf(v + bias1[nl]);
                    } else if (col < NQKV) {
                        const int nl = col - 8704;
                        const size_t off =
                            ((((size_t)b * HH + (nl >> 10)) * KT + ((nl >> 6) & 15)) * LL + l) * HW
                            + (nl & 63);
                        ((u16*)C2)[off] = f2bf(v + bias2[nl]);
                    }
                    // col >= NQKV: padding, discard
                }
            }
        }
    }
}

// ===========================================================================
// fp32 -> bf16 + swizzle, coalesced both sides. One thread per float4.
// The XOR permutes 16-B chunks within a 64-B line, so an 8-lane group's
// writes still cover one 64-B line exactly.
// Segments (float4 units): x 262144 | [Wq|Wk|Wv] 2162688 | Wo 65536
// Total 2490368 = 9728 blocks x 256.
// ===========================================================================
__global__ void cvt_swz(const float* __restrict__ x,  const float* __restrict__ Wq,
                        const float* __restrict__ Wk, const float* __restrict__ Wv,
                        const float* __restrict__ Wo,
                        u16* __restrict__ xb, u16* __restrict__ wb,
                        u16* __restrict__ wob)
{
    const int i = blockIdx.x * 256 + threadIdx.x;
    const float* src; u16* dst; int t;
    if (i < 262144) {
        t = i;
        src = x + ((size_t)t << 2);
        dst = xb;
    } else if (i < 2424832) {
        t = i - 262144;
        const int row = t >> 7;
        const int wel = (t & 127) << 2;
        if      (row <  512) src = Wq + (size_t)row * DM + wel;
        else if (row < 8704) src = Wk + (size_t)(row - 512) * DM + wel;
        else                 src = Wv + (size_t)(row - 8704) * DM + wel;
        dst = wb;
    } else {
        t = i - 2424832;
        src = Wo + ((size_t)t << 2);
        dst = wob;
    }
    const int row = t >> 7;              // 512 elements per row
    const int c8  = (t & 127) >> 1;      // 8-element chunk within row
    const int h4  = (t & 1) << 2;        // which half of the chunk
    const int s   = (row >> 1) & 3;
    const int oc  = (c8 & ~3) | ((c8 & 3) ^ s);
    float4 v = *(const float4*)src;
    ushort4v o = { f2bf(v.x), f2bf(v.y), f2bf(v.z), f2bf(v.w) };
    *(ushort4v*)(dst + ((size_t)row << 9) + (oc << 3) + h4) = o;
}

// ===========================================================================
// attention gather: 256 thr = 32 l's x 8 o-groups, grid = B*H*(L/32) = 512.
// Writes attnb SWIZZLED (it is the A matrix of the out-projection GEMM).
// ===========================================================================
__global__ __launch_bounds__(256) void attn_bf16(
    const u16* __restrict__ qb,     // (B,L,512) bf16 row-major
    const u16* __restrict__ kbuf,   // (B,H,K,L,64) bf16
    const u16* __restrict__ vbuf,
    const float* __restrict__ bk,   // (H,K,64) fp32
    const float* __restrict__ bv,
    u16* __restrict__ attnb)        // (B,L,512) bf16 swizzled
{
    const int tid = threadIdx.x;
    const int j  = tid & 7;          // o-group (8 o's)
    const int ll = tid >> 3;         // 0..31
    const int bid = blockIdx.x;
    const int h = bid & 7;
    const int t = (bid >> 3) & 31;
    const int b = bid >> 8;
    const int l = (t << 5) + ll;
    const int dil = c_dil[h];

    float qf[8];
    {
        ushort8v qv = *(const ushort8v*)(qb + ((size_t)(b * LL + l) * DM) + h * HW + (j << 3));
#pragma unroll
        for (int z = 0; z < 8; ++z) qf[z] = bf2f(qv[z]);
    }

    const size_t bh = ((size_t)b * HH + h) * KT;
    float lg[KT];
#pragma unroll
    for (int k = 0; k < KT; ++k) {
        const int src = l - (KT - 1 - k) * dil;
        float p = 0.f;
        if (src >= 0) {
            ushort8v kv = *(const ushort8v*)(kbuf + ((bh + k) * LL + src) * HW + (j << 3));
#pragma unroll
            for (int z = 0; z < 8; ++z) p += qf[z] * bf2f(kv[z]);
        } else {
            const float* bp = bk + (h * KT + k) * HW + (j << 3);
#pragma unroll
            for (int z = 0; z < 8; ++z) p += qf[z] * bp[z];
        }
        p += __shfl_xor(p, 1);
        p += __shfl_xor(p, 2);
        p += __shfl_xor(p, 4);
        lg[k] = p;
    }

    float m = lg[0];
#pragma unroll
    for (int k = 1; k < KT; ++k) m = fmaxf(m, lg[k]);
    float s = 0.f;
#pragma unroll
    for (int k = 0; k < KT; ++k) { lg[k] = __expf(lg[k] - m); s += lg[k]; }
    const float inv = 1.f / s;

    float acc[8];
#pragma unroll
    for (int z = 0; z < 8; ++z) acc[z] = 0.f;
#pragma unroll
    for (int k = 0; k < KT; ++k) {
        const int src = l - (KT - 1 - k) * dil;
        const float sc = lg[k] * inv;
        if (src >= 0) {
            ushort8v vv = *(const ushort8v*)(vbuf + ((bh + k) * LL + src) * HW + (j << 3));
#pragma unroll
            for (int z = 0; z < 8; ++z) acc[z] = fmaf(sc, bf2f(vv[z]), acc[z]);
        } else {
            const float* bp = bv + (h * KT + k) * HW + (j << 3);
#pragma unroll
            for (int z = 0; z < 8; ++z) acc[z] = fmaf(sc, bp[z], acc[z]);
        }
    }

    ushort8v o;
#pragma unroll
    for (int z = 0; z < 8; ++z) o[z] = f2bf(acc[z] * 0.125f);
    // swizzled store: orig 8-chunk index k8 = h*8+j goes to stored chunk
    // (k8&3)^s within its 32-block, s = (l>>1)&3
    const int row = b * LL + l;
    const int k8 = h * 8 + j;
    const int sw = ((k8 & 3) ^ ((l >> 1) & 3)) << 3;
    *(ushort8v*)(attnb + (size_t)row * DM + ((k8 >> 2) << 5) + sw) = o;
}

// ===========================================================================
// ------------------- round-1 fp32 fallback (small ws) ----------------------
// ===========================================================================
__global__ __launch_bounds__(256, 2) void gemm_nt_bias(
    const float* __restrict__ A, const float* __restrict__ Bm,
    const float* __restrict__ bias, float* __restrict__ C,
    int M, int N, int Kd)
{
    __shared__ float As[16][68];
    __shared__ float Bs[16][68];
    const int tid = threadIdx.x;
    const int tx = tid & 15, ty = tid >> 4;
    const int r0 = blockIdx.y << 6, c0 = blockIdx.x << 6;
    const int lr = tid >> 2, k4 = (tid & 3) << 2;
    const float* Ap = A  + (size_t)(r0 + lr) * Kd + k4;
    const float* Bp = Bm + (size_t)(c0 + lr) * Kd + k4;
    float acc[4][4];
#pragma unroll
    for (int i = 0; i < 4; ++i)
#pragma unroll
        for (int j = 0; j < 4; ++j) acc[i][j] = 0.f;
    for (int d0 = 0; d0 < Kd; d0 += 16) {
        float4 av = *(const float4*)(Ap + d0);
        float4 bv = *(const float4*)(Bp + d0);
        As[k4 + 0][lr] = av.x; As[k4 + 1][lr] = av.y;
        As[k4 + 2][lr] = av.z; As[k4 + 3][lr] = av.w;
        Bs[k4 + 0][lr] = bv.x; Bs[k4 + 1][lr] = bv.y;
        Bs[k4 + 2][lr] = bv.z; Bs[k4 + 3][lr] = bv.w;
        __syncthreads();
#pragma unroll
        for (int dd = 0; dd < 16; ++dd) {
            float4 a4 = *(const float4*)&As[dd][ty << 2];
            float4 b4 = *(const float4*)&Bs[dd][tx << 2];
            float ar[4] = {a4.x, a4.y, a4.z, a4.w};
            float br[4] = {b4.x, b4.y, b4.z, b4.w};
#pragma unroll
            for (int i = 0; i < 4; ++i)
#pragma unroll
                for (int j = 0; j < 4; ++j)
                    acc[i][j] = fmaf(ar[i], br[j], acc[i][j]);
        }
        __syncthreads();
    }
#pragma unroll
    for (int i = 0; i < 4; ++i) {
        float4 o;
        const int c = c0 + (tx << 2);
        o.x = acc[i][0] + bias[c + 0];
        o.y = acc[i][1] + bias[c + 1];
        o.z = acc[i][2] + bias[c + 2];
        o.w = acc[i][3] + bias[c + 3];
        *(float4*)&C[(size_t)(r0 + (ty << 2) + i) * N + c] = o;
    }
}

__device__ __forceinline__ void tile_gemm_f32(
    const float* __restrict__ xb, int src, bool ok,
    const float* __restrict__ wrow,
    int lr, int k4, int tx, int ty,
    float (&As)[16][68], float (&Ws)[16][68], float (&acc)[4][4])
{
#pragma unroll
    for (int i = 0; i < 4; ++i)
#pragma unroll
        for (int j = 0; j < 4; ++j) acc[i][j] = 0.f;
    const float* xrow = xb + (size_t)(ok ? src : 0) * DM + k4;
    for (int d0 = 0; d0 < DM; d0 += 16) {
        float4 av = make_float4(0.f, 0.f, 0.f, 0.f);
        if (ok) av = *(const float4*)(xrow + d0);
        float4 wv = *(const float4*)(wrow + d0);
        As[k4 + 0][lr] = av.x; As[k4 + 1][lr] = av.y;
        As[k4 + 2][lr] = av.z; As[k4 + 3][lr] = av.w;
        Ws[k4 + 0][lr] = wv.x; Ws[k4 + 1][lr] = wv.y;
        Ws[k4 + 2][lr] = wv.z; Ws[k4 + 3][lr] = wv.w;
        __syncthreads();
#pragma unroll
        for (int dd = 0; dd < 16; ++dd) {
            float4 a4 = *(const float4*)&As[dd][ty << 2];
            float4 b4 = *(const float4*)&Ws[dd][tx << 2];
            float ar[4] = {a4.x, a4.y, a4.z, a4.w};
            float br[4] = {b4.x, b4.y, b4.z, b4.w};
#pragma unroll
            for (int i = 0; i < 4; ++i)
#pragma unroll
                for (int j = 0; j < 4; ++j)
                    acc[i][j] = fmaf(ar[i], br[j], acc[i][j]);
        }
        __syncthreads();
    }
}

__global__ __launch_bounds__(256, 2) void attn_kernel(
    const float* __restrict__ x, const float* __restrict__ q,
    const float* __restrict__ Wk, const float* __restrict__ bk,
    const float* __restrict__ Wv, const float* __restrict__ bv,
    float* __restrict__ attn)
{
    __shared__ float As[16][68];
    __shared__ float Ws[16][68];
    __shared__ float qs[64][68];
    __shared__ float lg[64][17];
    __shared__ float red[64][17];
    const int tid = threadIdx.x;
    const int tx = tid & 15, ty = tid >> 4;
    const int bid = blockIdx.x;
    const int h = bid & 7, t = (bid >> 3) & 15, b = bid >> 7;
    const int l0 = t << 6;
    const int dil = c_dil[h];
    const int lr = tid >> 2, k4 = (tid & 3) << 2;
    for (int i = tid; i < 64 * 16; i += 256) {
        int l = i >> 4, o4 = (i & 15) << 2;
        float4 v = *(const float4*)&q[((size_t)(b * LL + l0 + l) * HH + h) * HW + o4];
        *(float4*)&qs[l][o4] = v;
    }
    const float* xb  = x  + (size_t)b * LL * DM;
    const float* Wkh = Wk + (size_t)h * KT * HW * DM;
    const float* Wvh = Wv + (size_t)h * KT * HW * DM;
    const float* bkh = bk + h * KT * HW;
    const float* bvh = bv + h * KT * HW;
    float acc[4][4];
    for (int kk = 0; kk < KT; ++kk) {
        const int src = l0 + lr - (KT - 1 - kk) * dil;
        const bool ok = (src >= 0) && (src < LL);
        tile_gemm_f32(xb, src, ok, Wkh + (size_t)(kk * HW + lr) * DM + k4,
                      lr, k4, tx, ty, As, Ws, acc);
        const float* bkp = bkh + kk * HW + (tx << 2);
#pragma unroll
        for (int i = 0; i < 4; ++i) {
            float p = 0.f;
#pragma unroll
            for (int j = 0; j < 4; ++j)
                p += (acc[i][j] + bkp[j]) * qs[(ty << 2) + i][(tx << 2) + j];
            red[(ty << 2) + i][tx] = p;
        }
        __syncthreads();
        if (tid < 64) {
            float s = 0.f;
#pragma unroll
            for (int u = 0; u < 16; ++u) s += red[tid][u];
            lg[tid][kk] = s;
        }
        __syncthreads();
    }
    if (tid < 64) {
        float m = lg[tid][0];
#pragma unroll
        for (int u = 1; u < KT; ++u) m = fmaxf(m, lg[tid][u]);
        float s = 0.f;
#pragma unroll
        for (int u = 0; u < KT; ++u) {
            float e = expf(lg[tid][u] - m);
            lg[tid][u] = e; s += e;
        }
        float inv = 1.f / s;
#pragma unroll
        for (int u = 0; u < KT; ++u) lg[tid][u] *= inv;
    }
    __syncthreads();
    float vacc[4][4];
#pragma unroll
    for (int i = 0; i < 4; ++i)
#pragma unroll
        for (int j = 0; j < 4; ++j) vacc[i][j] = 0.f;
    for (int kk = 0; kk < KT; ++kk) {
        const int src = l0 + lr - (KT - 1 - kk) * dil;
        const bool ok = (src >= 0) && (src < LL);
        tile_gemm_f32(xb, src, ok, Wvh + (size_t)(kk * HW + lr) * DM + k4,
                      lr, k4, tx, ty, As, Ws, acc);
        const float* bvp = bvh + kk * HW + (tx << 2);
#pragma unroll
        for (int i = 0; i < 4; ++i) {
            float sc = lg[(ty << 2) + i][kk];
#pragma unroll
            for (int j = 0; j < 4; ++j)
                vacc[i][j] = fmaf(sc, acc[i][j] + bvp[j], vacc[i][j]);
        }
    }
#pragma unroll
    for (int i = 0; i < 4; ++i) {
        float4 o;
        o.x = vacc[i][0] * 0.125f;
        o.y = vacc[i][1] * 0.125f;
        o.z = vacc[i][2] * 0.125f;
        o.w = vacc[i][3] * 0.125f;
        *(float4*)&attn[((size_t)(b * LL + l0 + (ty << 2) + i) * HH + h) * HW + (tx << 2)] = o;
    }
}

// ===========================================================================
extern "C" void kernel_launch(void* const* d_in, const int* in_sizes, int n_in,
                              void* d_out, int out_size, void* d_ws, size_t ws_size,
                              hipStream_t stream)
{
    const float* x  = (const float*)d_in[0];
    const float* Wq = (const float*)d_in[1];
    const float* bq = (const float*)d_in[2];
    const float* Wk = (const float*)d_in[3];
    const float* bk = (const float*)d_in[4];
    const float* Wv = (const float*)d_in[5];
    const float* bv = (const float*)d_in[6];
    const float* Wo = (const float*)d_in[7];
    const float* bo = (const float*)d_in[8];
    float* out = (float*)d_out;

    const int M = BD * LL;  // 2048

    // ws layout (ushort elements) for the fast path
    const size_t N_X   = (size_t)BD * LL * DM;            // 1,048,576
    const size_t N_WB  = (size_t)NPAD * DM;               // 8,912,896 (padded)
    const size_t N_WO  = (size_t)DM * DM;                 //   262,144
    const size_t N_KV  = (size_t)BD * HH * KT * LL * HW;  // 16,777,216
    const size_t NEED  = (N_X + N_WB + N_WO + 2 * N_X + 2 * N_KV) * 2;

    if (ws_size >= NEED) {
        u16* xb    = (u16*)d_ws;
        u16* wb    = xb    + N_X;      // [Wq|Wk|Wv] swizzled, NPAD x 512
        u16* wob   = wb    + N_WB;
        u16* qb    = wob   + N_WO;
        u16* attnb = qb    + N_X;
        u16* kbuf  = attnb + N_X;
        u16* vbuf  = kbuf  + N_KV;

        cvt_swz<<<9728, 256, 0, stream>>>(x, Wq, Wk, Wv, Wo, xb, wb, wob);

        // [q|k|v] = x * [Wq|Wk|Wv]^T + bias  (N padded to 17408, XCD-pinned)
        gemm_bf16<<<2176, 256, 0, stream>>>(
            xb, wb, NPAD, bq, bk, bv, qb, kbuf, vbuf, 2);

        // gather + softmax + weighted sum -> attnb (swizzled)
        attn_bf16<<<BD * HH * (LL / 32), 256, 0, stream>>>(
            qb, kbuf, vbuf, bk, bv, attnb);

        // out = attn * Wo^T + bo -> fp32
        gemm_bf16<<<dim3(4, 16), 256, 0, stream>>>(
            attnb, wob, DM, bo, nullptr, nullptr, out, nullptr, nullptr, 0);
    } else {
        // fp32 fallback (round-1 path, 8 MB ws)
        float* qws = (float*)d_ws;
        float* aws = qws + (size_t)BD * LL * HH * HW;
        gemm_nt_bias<<<dim3((HH * HW) / 64, M / 64), 256, 0, stream>>>(
            x, Wq, bq, qws, M, HH * HW, DM);
        attn_kernel<<<BD * HH * (LL / 64), 256, 0, stream>>>(
            x, qws, Wk, bk, Wv, bv, aws);
        gemm_nt_bias<<<dim3(DM / 64, M / 64), 256, 0, stream>>>(
            aws, Wo, bo, out, M, DM, HH * HW);
    }
}

// Round 5
// 200.751 us; speedup vs baseline: 5.1549x; 1.0210x over previous
//
#include <hip/hip_runtime.h>

// LCSA: dilated local-window self-attention.
// B=2, L=1024, D=512, H=8, HEAD_W=64, KERNEL=16, dilations {1,1,2,2,4,4,8,8},
// MODE=forward -> src(l,k) = l - (15-k)*dil, zero-padded outside [0,L).
//
// R5 fast path:
//   cvt_swz:  fp32->bf16 + per-row XOR chunk swizzle (coalesced both sides):
//             within each 64-B line: stored chunk c = orig chunk c^((row>>1)&3)
//   gemm_bf16 mode2: [q|k|v] = x*[Wq|Wk|Wv]^T + bias, 2-D grid dim3(136,16)
//             (x%8==0 so HW round-robin pins each XCD to 17 fixed B-tiles;
//              4 pad tiles early-exit). BK=64: 8 K-iterations, 32 MFMA/iter,
//             split-kb LDS layout keeps the conflict-free 2-way bank pattern.
//   attn_bf16: gather + softmax + weighted sum; writes attnb SWIZZLED
//   gemm_bf16 mode0: out = attn*Wo^T + bo (fp32)
// Fallback: round-1 fp32 path (8 MB ws).

#define BD 2
#define LL 1024
#define DM 512
#define HH 8
#define KT 16
#define HW 64

#define NQKV 16896          // 512 q + 8192 k + 8192 v
#define NPAD 17408          // 136 tiles of 128 (8 XCDs x 17)

typedef unsigned short u16;
typedef unsigned int u32;
typedef __bf16 bf16x8 __attribute__((ext_vector_type(8)));
typedef float f32x4 __attribute__((ext_vector_type(4)));
typedef unsigned short ushort4v __attribute__((ext_vector_type(4)));
typedef unsigned short ushort8v __attribute__((ext_vector_type(8)));

__constant__ int c_dil[8] = {1, 1, 2, 2, 4, 4, 8, 8};

__device__ __forceinline__ float bf2f(u16 u) {
    return __builtin_bit_cast(float, (u32)u << 16);
}
__device__ __forceinline__ u16 f2bf(float f) {   // round-to-nearest-even
    u32 u = __builtin_bit_cast(u32, f);
    return (u16)((u + 0x7fffu + ((u >> 16) & 1u)) >> 16);
}

// async global->LDS, 16 B per lane; lds dest must be (uniform base + lane*16)
__device__ __forceinline__ void gl_lds16(const u16* g, u16* l) {
    __builtin_amdgcn_global_load_lds(
        (__attribute__((address_space(1))) void*)g,
        (__attribute__((address_space(3))) void*)l, 16, 0, 0);
}

// ===========================================================================
// bf16 NT GEMM, 128x128 tile, K=512, BK=64, 256 thr (4 waves, 64x64 each),
// 16x16x32 MFMA. A and B stored SWIZZLED (see cvt_swz).
// mode 0: C0 fp32 row-major (stride N) + bias0
// mode 2: col <  512           -> qb  (C0, bf16 row-major stride 512, +bias0)
//         col in [512, 8704)   -> kbuf(C1, (B,H,K,L,64) scatter, +bias1)
//         col in [8704, 16896) -> vbuf(C2, same scatter, +bias2)
//         col >= 16896         -> block exits early (padding)
// ===========================================================================
__global__ __launch_bounds__(256, 4) void gemm_bf16(
    const u16* __restrict__ A, const u16* __restrict__ Bm,
    int N,
    const float* __restrict__ bias0, const float* __restrict__ bias1,
    const float* __restrict__ bias2,
    void* __restrict__ C0, void* __restrict__ C1, void* __restrict__ C2,
    int mode)
{
    const int m0 = blockIdx.y << 7;
    const int n0 = blockIdx.x << 7;
    if (mode == 2 && n0 >= NQKV) return;   // pad tiles (kept for XCD periodicity)

    // split-kb LDS: [kb][row][32 elems] -> 64-B rows, 2-way banks only
    __shared__ u16 As[2][128][32];
    __shared__ u16 Bs[2][128][32];

    const int tid  = threadIdx.x;
    const int wave = tid >> 6, lane = tid & 63;

    const int srow = lane >> 2;          // staging row within 16-row segment
    const int scol = (lane & 3) << 3;    // staging elem offset (8-elem chunks)
    const int mw = (wave >> 1) << 6;     // wave's 64x64 sub-tile
    const int nw = (wave & 1) << 6;
    const int lr = lane & 15;            // frag row/col within 16
    const int qg = lane >> 4;            // k-quarter (chunk of 8 within 32)
    // swizzled chunk offset: stored chunk (qg ^ s(row)), s(row)=(row>>1)&3
    const int ksw = ((qg ^ ((lr >> 1) & 3)) << 3);

    f32x4 acc[4][4];
#pragma unroll
    for (int i = 0; i < 4; ++i)
#pragma unroll
        for (int j = 0; j < 4; ++j) acc[i][j] = (f32x4){0.f, 0.f, 0.f, 0.f};

    for (int k0 = 0; k0 < 512; k0 += 64) {
        // stage 128x64 of A and B: 4 segments/thread each, one kb per wave-instr
#pragma unroll
        for (int u = 0; u < 4; ++u) {
            const int seg = wave * 4 + u;          // 0..15
            const int kb  = seg & 1;
            const int r   = ((seg >> 1) << 4) + srow;
            const int gof = k0 + kb * 32 + scol;
            gl_lds16(A  + (size_t)(m0 + r) * 512 + gof, &As[kb][r][scol]);
            gl_lds16(Bm + (size_t)(n0 + r) * 512 + gof, &Bs[kb][r][scol]);
        }
        __syncthreads();

#pragma unroll
        for (int kb = 0; kb < 2; ++kb) {
            bf16x8 af[4], bfr[4];
#pragma unroll
            for (int i = 0; i < 4; ++i)
                af[i] = *(const bf16x8*)&As[kb][mw + (i << 4) + lr][ksw];
#pragma unroll
            for (int j = 0; j < 4; ++j)
                bfr[j] = *(const bf16x8*)&Bs[kb][nw + (j << 4) + lr][ksw];
#pragma unroll
            for (int i = 0; i < 4; ++i)
#pragma unroll
                for (int j = 0; j < 4; ++j)
                    acc[i][j] = __builtin_amdgcn_mfma_f32_16x16x32_bf16(
                        af[i], bfr[j], acc[i][j], 0, 0, 0);
        }
        __syncthreads();
    }

    // epilogue: row = m0+mw+16i+qg*4+r, col = n0+nw+16j+lr
#pragma unroll
    for (int i = 0; i < 4; ++i) {
        const int rowb = m0 + mw + (i << 4) + (qg << 2);
#pragma unroll
        for (int j = 0; j < 4; ++j) {
            const int col = n0 + nw + (j << 4) + lr;
#pragma unroll
            for (int r = 0; r < 4; ++r) {
                const float v = acc[i][j][r];
                const int row = rowb + r;
                if (mode == 0) {
                    ((float*)C0)[(size_t)row * N + col] = v + bias0[col];
                } else {
                    const int b = row >> 10, l = row & 1023;
                    if (col < 512) {
                        ((u16*)C0)[(size_t)row * 512 + col] = f2bf(v + bias0[col]);
                    } else if (col < 8704) {
                        const int nl = col - 512;
                        const size_t off =
                            ((((size_t)b * HH + (nl >> 10)) * KT + ((nl >> 6) & 15)) * LL + l) * HW
                            + (nl & 63);
                        ((u16*)C1)[off] = f2bf(v + bias1[nl]);
                    } else {
                        const int nl = col - 8704;
                        const size_t off =
                            ((((size_t)b * HH + (nl >> 10)) * KT + ((nl >> 6) & 15)) * LL + l) * HW
                            + (nl & 63);
                        ((u16*)C2)[off] = f2bf(v + bias2[nl]);
                    }
                }
            }
        }
    }
}

// ===========================================================================
// fp32 -> bf16 + swizzle, coalesced both sides. One thread per float4.
// The XOR permutes 16-B chunks within a 64-B line, so an 8-lane group's
// writes still cover one 64-B line exactly.
// Segments (float4 units): x 262144 | [Wq|Wk|Wv] 2162688 | Wo 65536
// Total 2490368 = 9728 blocks x 256.
// ===========================================================================
__global__ void cvt_swz(const float* __restrict__ x,  const float* __restrict__ Wq,
                        const float* __restrict__ Wk, const float* __restrict__ Wv,
                        const float* __restrict__ Wo,
                        u16* __restrict__ xb, u16* __restrict__ wb,
                        u16* __restrict__ wob)
{
    const int i = blockIdx.x * 256 + threadIdx.x;
    const float* src; u16* dst; int t;
    if (i < 262144) {
        t = i;
        src = x + ((size_t)t << 2);
        dst = xb;
    } else if (i < 2424832) {
        t = i - 262144;
        const int row = t >> 7;
        const int wel = (t & 127) << 2;
        if      (row <  512) src = Wq + (size_t)row * DM + wel;
        else if (row < 8704) src = Wk + (size_t)(row - 512) * DM + wel;
        else                 src = Wv + (size_t)(row - 8704) * DM + wel;
        dst = wb;
    } else {
        t = i - 2424832;
        src = Wo + ((size_t)t << 2);
        dst = wob;
    }
    const int row = t >> 7;              // 512 elements per row
    const int c8  = (t & 127) >> 1;      // 8-element chunk within row
    const int h4  = (t & 1) << 2;        // which half of the chunk
    const int s   = (row >> 1) & 3;
    const int oc  = (c8 & ~3) | ((c8 & 3) ^ s);
    float4 v = *(const float4*)src;
    ushort4v o = { f2bf(v.x), f2bf(v.y), f2bf(v.z), f2bf(v.w) };
    *(ushort4v*)(dst + ((size_t)row << 9) + (oc << 3) + h4) = o;
}

// ===========================================================================
// attention gather: 256 thr = 32 l's x 8 o-groups, grid = B*H*(L/32) = 512.
// Writes attnb SWIZZLED (it is the A matrix of the out-projection GEMM).
// ===========================================================================
__global__ __launch_bounds__(256) void attn_bf16(
    const u16* __restrict__ qb,     // (B,L,512) bf16 row-major
    const u16* __restrict__ kbuf,   // (B,H,K,L,64) bf16
    const u16* __restrict__ vbuf,
    const float* __restrict__ bk,   // (H,K,64) fp32
    const float* __restrict__ bv,
    u16* __restrict__ attnb)        // (B,L,512) bf16 swizzled
{
    const int tid = threadIdx.x;
    const int j  = tid & 7;          // o-group (8 o's)
    const int ll = tid >> 3;         // 0..31
    const int bid = blockIdx.x;
    const int h = bid & 7;
    const int t = (bid >> 3) & 31;
    const int b = bid >> 8;
    const int l = (t << 5) + ll;
    const int dil = c_dil[h];

    float qf[8];
    {
        ushort8v qv = *(const ushort8v*)(qb + ((size_t)(b * LL + l) * DM) + h * HW + (j << 3));
#pragma unroll
        for (int z = 0; z < 8; ++z) qf[z] = bf2f(qv[z]);
    }

    const size_t bh = ((size_t)b * HH + h) * KT;
    float lg[KT];
#pragma unroll
    for (int k = 0; k < KT; ++k) {
        const int src = l - (KT - 1 - k) * dil;
        float p = 0.f;
        if (src >= 0) {
            ushort8v kv = *(const ushort8v*)(kbuf + ((bh + k) * LL + src) * HW + (j << 3));
#pragma unroll
            for (int z = 0; z < 8; ++z) p += qf[z] * bf2f(kv[z]);
        } else {
            const float* bp = bk + (h * KT + k) * HW + (j << 3);
#pragma unroll
            for (int z = 0; z < 8; ++z) p += qf[z] * bp[z];
        }
        p += __shfl_xor(p, 1);
        p += __shfl_xor(p, 2);
        p += __shfl_xor(p, 4);
        lg[k] = p;
    }

    float m = lg[0];
#pragma unroll
    for (int k = 1; k < KT; ++k) m = fmaxf(m, lg[k]);
    float s = 0.f;
#pragma unroll
    for (int k = 0; k < KT; ++k) { lg[k] = __expf(lg[k] - m); s += lg[k]; }
    const float inv = 1.f / s;

    float acc[8];
#pragma unroll
    for (int z = 0; z < 8; ++z) acc[z] = 0.f;
#pragma unroll
    for (int k = 0; k < KT; ++k) {
        const int src = l - (KT - 1 - k) * dil;
        const float sc = lg[k] * inv;
        if (src >= 0) {
            ushort8v vv = *(const ushort8v*)(vbuf + ((bh + k) * LL + src) * HW + (j << 3));
#pragma unroll
            for (int z = 0; z < 8; ++z) acc[z] = fmaf(sc, bf2f(vv[z]), acc[z]);
        } else {
            const float* bp = bv + (h * KT + k) * HW + (j << 3);
#pragma unroll
            for (int z = 0; z < 8; ++z) acc[z] = fmaf(sc, bp[z], acc[z]);
        }
    }

    ushort8v o;
#pragma unroll
    for (int z = 0; z < 8; ++z) o[z] = f2bf(acc[z] * 0.125f);
    // swizzled store: orig 8-chunk index k8 = h*8+j goes to stored chunk
    // (k8&3)^s within its 32-block, s = (l>>1)&3
    const int row = b * LL + l;
    const int k8 = h * 8 + j;
    const int sw = ((k8 & 3) ^ ((l >> 1) & 3)) << 3;
    *(ushort8v*)(attnb + (size_t)row * DM + ((k8 >> 2) << 5) + sw) = o;
}

// ===========================================================================
// ------------------- round-1 fp32 fallback (small ws) ----------------------
// ===========================================================================
__global__ __launch_bounds__(256, 2) void gemm_nt_bias(
    const float* __restrict__ A, const float* __restrict__ Bm,
    const float* __restrict__ bias, float* __restrict__ C,
    int M, int N, int Kd)
{
    __shared__ float As[16][68];
    __shared__ float Bs[16][68];
    const int tid = threadIdx.x;
    const int tx = tid & 15, ty = tid >> 4;
    const int r0 = blockIdx.y << 6, c0 = blockIdx.x << 6;
    const int lr = tid >> 2, k4 = (tid & 3) << 2;
    const float* Ap = A  + (size_t)(r0 + lr) * Kd + k4;
    const float* Bp = Bm + (size_t)(c0 + lr) * Kd + k4;
    float acc[4][4];
#pragma unroll
    for (int i = 0; i < 4; ++i)
#pragma unroll
        for (int j = 0; j < 4; ++j) acc[i][j] = 0.f;
    for (int d0 = 0; d0 < Kd; d0 += 16) {
        float4 av = *(const float4*)(Ap + d0);
        float4 bv = *(const float4*)(Bp + d0);
        As[k4 + 0][lr] = av.x; As[k4 + 1][lr] = av.y;
        As[k4 + 2][lr] = av.z; As[k4 + 3][lr] = av.w;
        Bs[k4 + 0][lr] = bv.x; Bs[k4 + 1][lr] = bv.y;
        Bs[k4 + 2][lr] = bv.z; Bs[k4 + 3][lr] = bv.w;
        __syncthreads();
#pragma unroll
        for (int dd = 0; dd < 16; ++dd) {
            float4 a4 = *(const float4*)&As[dd][ty << 2];
            float4 b4 = *(const float4*)&Bs[dd][tx << 2];
            float ar[4] = {a4.x, a4.y, a4.z, a4.w};
            float br[4] = {b4.x, b4.y, b4.z, b4.w};
#pragma unroll
            for (int i = 0; i < 4; ++i)
#pragma unroll
                for (int j = 0; j < 4; ++j)
                    acc[i][j] = fmaf(ar[i], br[j], acc[i][j]);
        }
        __syncthreads();
    }
#pragma unroll
    for (int i = 0; i < 4; ++i) {
        float4 o;
        const int c = c0 + (tx << 2);
        o.x = acc[i][0] + bias[c + 0];
        o.y = acc[i][1] + bias[c + 1];
        o.z = acc[i][2] + bias[c + 2];
        o.w = acc[i][3] + bias[c + 3];
        *(float4*)&C[(size_t)(r0 + (ty << 2) + i) * N + c] = o;
    }
}

__device__ __forceinline__ void tile_gemm_f32(
    const float* __restrict__ xb, int src, bool ok,
    const float* __restrict__ wrow,
    int lr, int k4, int tx, int ty,
    float (&As)[16][68], float (&Ws)[16][68], float (&acc)[4][4])
{
#pragma unroll
    for (int i = 0; i < 4; ++i)
#pragma unroll
        for (int j = 0; j < 4; ++j) acc[i][j] = 0.f;
    const float* xrow = xb + (size_t)(ok ? src : 0) * DM + k4;
    for (int d0 = 0; d0 < DM; d0 += 16) {
        float4 av = make_float4(0.f, 0.f, 0.f, 0.f);
        if (ok) av = *(const float4*)(xrow + d0);
        float4 wv = *(const float4*)(wrow + d0);
        As[k4 + 0][lr] = av.x; As[k4 + 1][lr] = av.y;
        As[k4 + 2][lr] = av.z; As[k4 + 3][lr] = av.w;
        Ws[k4 + 0][lr] = wv.x; Ws[k4 + 1][lr] = wv.y;
        Ws[k4 + 2][lr] = wv.z; Ws[k4 + 3][lr] = wv.w;
        __syncthreads();
#pragma unroll
        for (int dd = 0; dd < 16; ++dd) {
            float4 a4 = *(const float4*)&As[dd][ty << 2];
            float4 b4 = *(const float4*)&Ws[dd][tx << 2];
            float ar[4] = {a4.x, a4.y, a4.z, a4.w};
            float br[4] = {b4.x, b4.y, b4.z, b4.w};
#pragma unroll
            for (int i = 0; i < 4; ++i)
#pragma unroll
                for (int j = 0; j < 4; ++j)
                    acc[i][j] = fmaf(ar[i], br[j], acc[i][j]);
        }
        __syncthreads();
    }
}

__global__ __launch_bounds__(256, 2) void attn_kernel(
    const float* __restrict__ x, const float* __restrict__ q,
    const float* __restrict__ Wk, const float* __restrict__ bk,
    const float* __restrict__ Wv, const float* __restrict__ bv,
    float* __restrict__ attn)
{
    __shared__ float As[16][68];
    __shared__ float Ws[16][68];
    __shared__ float qs[64][68];
    __shared__ float lg[64][17];
    __shared__ float red[64][17];
    const int tid = threadIdx.x;
    const int tx = tid & 15, ty = tid >> 4;
    const int bid = blockIdx.x;
    const int h = bid & 7, t = (bid >> 3) & 15, b = bid >> 7;
    const int l0 = t << 6;
    const int dil = c_dil[h];
    const int lr = tid >> 2, k4 = (tid & 3) << 2;
    for (int i = tid; i < 64 * 16; i += 256) {
        int l = i >> 4, o4 = (i & 15) << 2;
        float4 v = *(const float4*)&q[((size_t)(b * LL + l0 + l) * HH + h) * HW + o4];
        *(float4*)&qs[l][o4] = v;
    }
    const float* xb  = x  + (size_t)b * LL * DM;
    const float* Wkh = Wk + (size_t)h * KT * HW * DM;
    const float* Wvh = Wv + (size_t)h * KT * HW * DM;
    const float* bkh = bk + h * KT * HW;
    const float* bvh = bv + h * KT * HW;
    float acc[4][4];
    for (int kk = 0; kk < KT; ++kk) {
        const int src = l0 + lr - (KT - 1 - kk) * dil;
        const bool ok = (src >= 0) && (src < LL);
        tile_gemm_f32(xb, src, ok, Wkh + (size_t)(kk * HW + lr) * DM + k4,
                      lr, k4, tx, ty, As, Ws, acc);
        const float* bkp = bkh + kk * HW + (tx << 2);
#pragma unroll
        for (int i = 0; i < 4; ++i) {
            float p = 0.f;
#pragma unroll
            for (int j = 0; j < 4; ++j)
                p += (acc[i][j] + bkp[j]) * qs[(ty << 2) + i][(tx << 2) + j];
            red[(ty << 2) + i][tx] = p;
        }
        __syncthreads();
        if (tid < 64) {
            float s = 0.f;
#pragma unroll
            for (int u = 0; u < 16; ++u) s += red[tid][u];
            lg[tid][kk] = s;
        }
        __syncthreads();
    }
    if (tid < 64) {
        float m = lg[tid][0];
#pragma unroll
        for (int u = 1; u < KT; ++u) m = fmaxf(m, lg[tid][u]);
        float s = 0.f;
#pragma unroll
        for (int u = 0; u < KT; ++u) {
            float e = expf(lg[tid][u] - m);
            lg[tid][u] = e; s += e;
        }
        float inv = 1.f / s;
#pragma unroll
        for (int u = 0; u < KT; ++u) lg[tid][u] *= inv;
    }
    __syncthreads();
    float vacc[4][4];
#pragma unroll
    for (int i = 0; i < 4; ++i)
#pragma unroll
        for (int j = 0; j < 4; ++j) vacc[i][j] = 0.f;
    for (int kk = 0; kk < KT; ++kk) {
        const int src = l0 + lr - (KT - 1 - kk) * dil;
        const bool ok = (src >= 0) && (src < LL);
        tile_gemm_f32(xb, src, ok, Wvh + (size_t)(kk * HW + lr) * DM + k4,
                      lr, k4, tx, ty, As, Ws, acc);
        const float* bvp = bvh + kk * HW + (tx << 2);
#pragma unroll
        for (int i = 0; i < 4; ++i) {
            float sc = lg[(ty << 2) + i][kk];
#pragma unroll
            for (int j = 0; j < 4; ++j)
                vacc[i][j] = fmaf(sc, acc[i][j] + bvp[j], vacc[i][j]);
        }
    }
#pragma unroll
    for (int i = 0; i < 4; ++i) {
        float4 o;
        o.x = vacc[i][0] * 0.125f;
        o.y = vacc[i][1] * 0.125f;
        o.z = vacc[i][2] * 0.125f;
        o.w = vacc[i][3] * 0.125f;
        *(float4*)&attn[((size_t)(b * LL + l0 + (ty << 2) + i) * HH + h) * HW + (tx << 2)] = o;
    }
}

// ===========================================================================
extern "C" void kernel_launch(void* const* d_in, const int* in_sizes, int n_in,
                              void* d_out, int out_size, void* d_ws, size_t ws_size,
                              hipStream_t stream)
{
    const float* x  = (const float*)d_in[0];
    const float* Wq = (const float*)d_in[1];
    const float* bq = (const float*)d_in[2];
    const float* Wk = (const float*)d_in[3];
    const float* bk = (const float*)d_in[4];
    const float* Wv = (const float*)d_in[5];
    const float* bv = (const float*)d_in[6];
    const float* Wo = (const float*)d_in[7];
    const float* bo = (const float*)d_in[8];
    float* out = (float*)d_out;

    const int M = BD * LL;  // 2048

    // ws layout (ushort elements) for the fast path
    const size_t N_X   = (size_t)BD * LL * DM;            // 1,048,576
    const size_t N_WB  = (size_t)NPAD * DM;               // 8,912,896 (padded)
    const size_t N_WO  = (size_t)DM * DM;                 //   262,144
    const size_t N_KV  = (size_t)BD * HH * KT * LL * HW;  // 16,777,216
    const size_t NEED  = (N_X + N_WB + N_WO + 2 * N_X + 2 * N_KV) * 2;

    if (ws_size >= NEED) {
        u16* xb    = (u16*)d_ws;
        u16* wb    = xb    + N_X;      // [Wq|Wk|Wv] swizzled, NPAD x 512
        u16* wob   = wb    + N_WB;
        u16* qb    = wob   + N_WO;
        u16* attnb = qb    + N_X;
        u16* kbuf  = attnb + N_X;
        u16* vbuf  = kbuf  + N_KV;

        cvt_swz<<<9728, 256, 0, stream>>>(x, Wq, Wk, Wv, Wo, xb, wb, wob);

        // [q|k|v] = x * [Wq|Wk|Wv]^T + bias; x-dim 136 (x%8==0, pad exits)
        gemm_bf16<<<dim3(136, 16), 256, 0, stream>>>(
            xb, wb, NPAD, bq, bk, bv, qb, kbuf, vbuf, 2);

        // gather + softmax + weighted sum -> attnb (swizzled)
        attn_bf16<<<BD * HH * (LL / 32), 256, 0, stream>>>(
            qb, kbuf, vbuf, bk, bv, attnb);

        // out = attn * Wo^T + bo -> fp32
        gemm_bf16<<<dim3(4, 16), 256, 0, stream>>>(
            attnb, wob, DM, bo, nullptr, nullptr, out, nullptr, nullptr, 0);
    } else {
        // fp32 fallback (round-1 path, 8 MB ws)
        float* qws = (float*)d_ws;
        float* aws = qws + (size_t)BD * LL * HH * HW;
        gemm_nt_bias<<<dim3((HH * HW) / 64, M / 64), 256, 0, stream>>>(
            x, Wq, bq, qws, M, HH * HW, DM);
        attn_kernel<<<BD * HH * (LL / 64), 256, 0, stream>>>(
            x, qws, Wk, bk, Wv, bv, aws);
        gemm_nt_bias<<<dim3(DM / 64, M / 64), 256, 0, stream>>>(
            aws, Wo, bo, out, M, DM, HH * HW);
    }
}

// Round 6
// 172.384 us; speedup vs baseline: 6.0031x; 1.1646x over previous
//
#include <hip/hip_runtime.h>

// LCSA: dilated local-window self-attention.
// B=2, L=1024, D=512, H=8, HEAD_W=64, KERNEL=16, dilations {1,1,2,2,4,4,8,8},
// MODE=forward -> src(l,k) = l - (15-k)*dil, zero-padded outside [0,L).
//
// R6 fast path:
//   cvt_swz:  fp32->bf16 + per-row XOR chunk swizzle (coalesced both sides)
//   gemm_bf16: qkv = x*[Wq|Wk|Wv]^T + bias -> NATURAL row-major bf16
//              (2048 x 16896), BK=32, grid dim3(136,16) (x%8==0 for XCD
//              periodicity, 4 pad tiles early-exit), bias region tile-uniform.
//   attn_bf16: gather from natural qkv + softmax + weighted sum -> attnb (swz)
//   gemm_out:  out = attnb*Wo^T + bo, 64x64 tiles, 256 blocks, fp32 out
// Fallback: round-1 fp32 path (8 MB ws).

#define BD 2
#define LL 1024
#define DM 512
#define HH 8
#define KT 16
#define HW 64

#define NQKV 16896          // 512 q + 8192 k + 8192 v

typedef unsigned short u16;
typedef unsigned int u32;
typedef __bf16 bf16x8 __attribute__((ext_vector_type(8)));
typedef float f32x4 __attribute__((ext_vector_type(4)));
typedef unsigned short ushort4v __attribute__((ext_vector_type(4)));
typedef unsigned short ushort8v __attribute__((ext_vector_type(8)));

__constant__ int c_dil[8] = {1, 1, 2, 2, 4, 4, 8, 8};

__device__ __forceinline__ float bf2f(u16 u) {
    return __builtin_bit_cast(float, (u32)u << 16);
}
__device__ __forceinline__ u16 f2bf(float f) {   // round-to-nearest-even
    u32 u = __builtin_bit_cast(u32, f);
    return (u16)((u + 0x7fffu + ((u >> 16) & 1u)) >> 16);
}

// async global->LDS, 16 B per lane; lds dest must be (uniform base + lane*16)
__device__ __forceinline__ void gl_lds16(const u16* g, u16* l) {
    __builtin_amdgcn_global_load_lds(
        (__attribute__((address_space(1))) void*)g,
        (__attribute__((address_space(3))) void*)l, 16, 0, 0);
}

// ===========================================================================
// Fused qkv projection GEMM: C(2048 x NQKV bf16, row-major) =
//   x(2048x512) * [Wq|Wk|Wv]^T + bias.  128x128 tile, BK=32,
//   4 waves (64x64 each), 16x16x32 MFMA. A,B stored swizzled.
//   grid dim3(136,16); tiles with n0>=NQKV exit (pad for XCD periodicity).
// ===========================================================================
__global__ __launch_bounds__(256, 4) void gemm_bf16(
    const u16* __restrict__ A, const u16* __restrict__ Bm,
    const float* __restrict__ bq, const float* __restrict__ bk,
    const float* __restrict__ bv, u16* __restrict__ C)
{
    const int m0 = blockIdx.y << 7;
    const int n0 = blockIdx.x << 7;
    if (n0 >= NQKV) return;             // pad tiles

    __shared__ u16 As[128 * 32];
    __shared__ u16 Bs[128 * 32];

    const int tid  = threadIdx.x;
    const int wave = tid >> 6, lane = tid & 63;
    const int r0 = tid >> 2;            // staging row 0..63 (round 0)
    const int cc = (tid & 3) << 3;      // staging k-offset (elements)
    const int mw = (wave >> 1) << 6;
    const int nw = (wave & 1) << 6;
    const int lr = lane & 15;
    const int qg = lane >> 4;
    const int ksw = ((qg ^ ((lr >> 1) & 3)) << 3);   // swizzled chunk

    const u16* Ag = A  + (size_t)(m0 + r0) * DM + cc;
    const u16* Bg = Bm + (size_t)(n0 + r0) * DM + cc;
    u16* lA = &As[0] + tid * 8;
    u16* lB = &Bs[0] + tid * 8;

    f32x4 acc[4][4];
#pragma unroll
    for (int i = 0; i < 4; ++i)
#pragma unroll
        for (int j = 0; j < 4; ++j) acc[i][j] = (f32x4){0.f, 0.f, 0.f, 0.f};

    for (int k0 = 0; k0 < DM; k0 += 32) {
        gl_lds16(Ag + k0, lA);
        gl_lds16(Ag + k0 + (size_t)64 * DM, lA + 64 * 32);
        gl_lds16(Bg + k0, lB);
        gl_lds16(Bg + k0 + (size_t)64 * DM, lB + 64 * 32);
        __syncthreads();

        bf16x8 af[4], bfr[4];
#pragma unroll
        for (int i = 0; i < 4; ++i)
            af[i] = *(const bf16x8*)&As[(mw + (i << 4) + lr) * 32 + ksw];
#pragma unroll
        for (int j = 0; j < 4; ++j)
            bfr[j] = *(const bf16x8*)&Bs[(nw + (j << 4) + lr) * 32 + ksw];
#pragma unroll
        for (int i = 0; i < 4; ++i)
#pragma unroll
            for (int j = 0; j < 4; ++j)
                acc[i][j] = __builtin_amdgcn_mfma_f32_16x16x32_bf16(
                    af[i], bfr[j], acc[i][j], 0, 0, 0);
        __syncthreads();
    }

    // bias region is tile-uniform (tiles 0..3 q, 4..67 k, 68..131 v)
    const float* bias; int cb;
    if      (n0 <  512) { bias = bq; cb = 0;    }
    else if (n0 < 8704) { bias = bk; cb = 512;  }
    else                { bias = bv; cb = 8704; }

    // C row = m0+mw+16i+4qg+r, col = n0+nw+16j+lr
#pragma unroll
    for (int i = 0; i < 4; ++i) {
        const int rowb = m0 + mw + (i << 4) + (qg << 2);
#pragma unroll
        for (int j = 0; j < 4; ++j) {
            const int col = n0 + nw + (j << 4) + lr;
            const float bs = bias[col - cb];
#pragma unroll
            for (int r = 0; r < 4; ++r)
                C[(size_t)(rowb + r) * NQKV + col] = f2bf(acc[i][j][r] + bs);
        }
    }
}

// ===========================================================================
// Output projection: out(2048x512 fp32) = attnb(2048x512 swz) * Wo^T(512x512
// swz) + bo. 64x64 tiles, grid (8,32) = 256 blocks, 4 waves (16x64 each).
// ===========================================================================
__global__ __launch_bounds__(256, 4) void gemm_out(
    const u16* __restrict__ A, const u16* __restrict__ Bm,
    const float* __restrict__ bias, float* __restrict__ C)
{
    __shared__ u16 As[64 * 32];
    __shared__ u16 Bs[64 * 32];

    const int tid  = threadIdx.x;
    const int wave = tid >> 6, lane = tid & 63;
    const int m0 = blockIdx.y << 6, n0 = blockIdx.x << 6;
    const int r0 = tid >> 2, cc = (tid & 3) << 3;
    const int mw = wave << 4;           // wave's 16-row band
    const int lr = lane & 15, qg = lane >> 4;
    const int ksw = ((qg ^ ((lr >> 1) & 3)) << 3);

    const u16* Ag = A  + (size_t)(m0 + r0) * DM + cc;
    const u16* Bg = Bm + (size_t)(n0 + r0) * DM + cc;
    u16* lA = &As[0] + tid * 8;
    u16* lB = &Bs[0] + tid * 8;

    f32x4 acc[4];
#pragma unroll
    for (int j = 0; j < 4; ++j) acc[j] = (f32x4){0.f, 0.f, 0.f, 0.f};

    for (int k0 = 0; k0 < DM; k0 += 32) {
        gl_lds16(Ag + k0, lA);
        gl_lds16(Bg + k0, lB);
        __syncthreads();
        bf16x8 af = *(const bf16x8*)&As[(mw + lr) * 32 + ksw];
#pragma unroll
        for (int j = 0; j < 4; ++j) {
            bf16x8 bfr = *(const bf16x8*)&Bs[((j << 4) + lr) * 32 + ksw];
            acc[j] = __builtin_amdgcn_mfma_f32_16x16x32_bf16(af, bfr, acc[j], 0, 0, 0);
        }
        __syncthreads();
    }

    // C row = m0+mw+4qg+r, col = n0+16j+lr
#pragma unroll
    for (int j = 0; j < 4; ++j) {
        const int col = n0 + (j << 4) + lr;
        const float bs = bias[col];
#pragma unroll
        for (int r = 0; r < 4; ++r)
            C[(size_t)(m0 + mw + (qg << 2) + r) * DM + col] = acc[j][r] + bs;
    }
}

// ===========================================================================
// fp32 -> bf16 + swizzle, coalesced both sides. One thread per float4.
// Segments (float4 units): x 262144 | [Wq|Wk|Wv] 2162688 | Wo 65536
// Total 2490368 = 9728 blocks x 256.
// ===========================================================================
__global__ void cvt_swz(const float* __restrict__ x,  const float* __restrict__ Wq,
                        const float* __restrict__ Wk, const float* __restrict__ Wv,
                        const float* __restrict__ Wo,
                        u16* __restrict__ xb, u16* __restrict__ wb,
                        u16* __restrict__ wob)
{
    const int i = blockIdx.x * 256 + threadIdx.x;
    const float* src; u16* dst; int t;
    if (i < 262144) {
        t = i;
        src = x + ((size_t)t << 2);
        dst = xb;
    } else if (i < 2424832) {
        t = i - 262144;
        const int row = t >> 7;
        const int wel = (t & 127) << 2;
        if      (row <  512) src = Wq + (size_t)row * DM + wel;
        else if (row < 8704) src = Wk + (size_t)(row - 512) * DM + wel;
        else                 src = Wv + (size_t)(row - 8704) * DM + wel;
        dst = wb;
    } else {
        t = i - 2424832;
        src = Wo + ((size_t)t << 2);
        dst = wob;
    }
    const int row = t >> 7;              // 512 elements per row
    const int c8  = (t & 127) >> 1;      // 8-element chunk within row
    const int h4  = (t & 1) << 2;        // which half of the chunk
    const int s   = (row >> 1) & 3;
    const int oc  = (c8 & ~3) | ((c8 & 3) ^ s);
    float4 v = *(const float4*)src;
    ushort4v o = { f2bf(v.x), f2bf(v.y), f2bf(v.z), f2bf(v.w) };
    *(ushort4v*)(dst + ((size_t)row << 9) + (oc << 3) + h4) = o;
}

// ===========================================================================
// attention gather: 256 thr = 32 l's x 8 o-groups, grid = B*H*(L/32) = 512.
// Reads q/k/v from natural qkv (stride NQKV); writes attnb SWIZZLED.
// ===========================================================================
__global__ __launch_bounds__(256) void attn_bf16(
    const u16* __restrict__ qkv,    // (B*L, NQKV) bf16
    const float* __restrict__ bk,   // (H,K,64) fp32
    const float* __restrict__ bv,
    u16* __restrict__ attnb)        // (B,L,512) bf16 swizzled
{
    const int tid = threadIdx.x;
    const int j  = tid & 7;          // o-group (8 o's)
    const int ll = tid >> 3;         // 0..31
    const int bid = blockIdx.x;
    const int h = bid & 7;
    const int t = (bid >> 3) & 31;
    const int b = bid >> 8;
    const int l = (t << 5) + ll;
    const int dil = c_dil[h];

    const int hko = h * (KT * HW);   // head offset within k/v region

    float qf[8];
    {
        ushort8v qv = *(const ushort8v*)(qkv + (size_t)(b * LL + l) * NQKV
                                         + h * HW + (j << 3));
#pragma unroll
        for (int z = 0; z < 8; ++z) qf[z] = bf2f(qv[z]);
    }

    float lg[KT];
#pragma unroll
    for (int k = 0; k < KT; ++k) {
        const int src = l - (KT - 1 - k) * dil;
        float p = 0.f;
        if (src >= 0) {
            ushort8v kv = *(const ushort8v*)(qkv + (size_t)(b * LL + src) * NQKV
                                             + 512 + hko + k * HW + (j << 3));
#pragma unroll
            for (int z = 0; z < 8; ++z) p += qf[z] * bf2f(kv[z]);
        } else {
            const float* bp = bk + hko + k * HW + (j << 3);
#pragma unroll
            for (int z = 0; z < 8; ++z) p += qf[z] * bp[z];
        }
        p += __shfl_xor(p, 1);
        p += __shfl_xor(p, 2);
        p += __shfl_xor(p, 4);
        lg[k] = p;
    }

    float m = lg[0];
#pragma unroll
    for (int k = 1; k < KT; ++k) m = fmaxf(m, lg[k]);
    float s = 0.f;
#pragma unroll
    for (int k = 0; k < KT; ++k) { lg[k] = __expf(lg[k] - m); s += lg[k]; }
    const float inv = 1.f / s;

    float acc[8];
#pragma unroll
    for (int z = 0; z < 8; ++z) acc[z] = 0.f;
#pragma unroll
    for (int k = 0; k < KT; ++k) {
        const int src = l - (KT - 1 - k) * dil;
        const float sc = lg[k] * inv;
        if (src >= 0) {
            ushort8v vv = *(const ushort8v*)(qkv + (size_t)(b * LL + src) * NQKV
                                             + 8704 + hko + k * HW + (j << 3));
#pragma unroll
            for (int z = 0; z < 8; ++z) acc[z] = fmaf(sc, bf2f(vv[z]), acc[z]);
        } else {
            const float* bp = bv + hko + k * HW + (j << 3);
#pragma unroll
            for (int z = 0; z < 8; ++z) acc[z] = fmaf(sc, bp[z], acc[z]);
        }
    }

    ushort8v o;
#pragma unroll
    for (int z = 0; z < 8; ++z) o[z] = f2bf(acc[z] * 0.125f);
    const int row = b * LL + l;
    const int k8 = h * 8 + j;
    const int sw = ((k8 & 3) ^ ((l >> 1) & 3)) << 3;
    *(ushort8v*)(attnb + (size_t)row * DM + ((k8 >> 2) << 5) + sw) = o;
}

// ===========================================================================
// ------------------- round-1 fp32 fallback (small ws) ----------------------
// ===========================================================================
__global__ __launch_bounds__(256, 2) void gemm_nt_bias(
    const float* __restrict__ A, const float* __restrict__ Bm,
    const float* __restrict__ bias, float* __restrict__ C,
    int M, int N, int Kd)
{
    __shared__ float As[16][68];
    __shared__ float Bs[16][68];
    const int tid = threadIdx.x;
    const int tx = tid & 15, ty = tid >> 4;
    const int r0 = blockIdx.y << 6, c0 = blockIdx.x << 6;
    const int lr = tid >> 2, k4 = (tid & 3) << 2;
    const float* Ap = A  + (size_t)(r0 + lr) * Kd + k4;
    const float* Bp = Bm + (size_t)(c0 + lr) * Kd + k4;
    float acc[4][4];
#pragma unroll
    for (int i = 0; i < 4; ++i)
#pragma unroll
        for (int j = 0; j < 4; ++j) acc[i][j] = 0.f;
    for (int d0 = 0; d0 < Kd; d0 += 16) {
        float4 av = *(const float4*)(Ap + d0);
        float4 bv = *(const float4*)(Bp + d0);
        As[k4 + 0][lr] = av.x; As[k4 + 1][lr] = av.y;
        As[k4 + 2][lr] = av.z; As[k4 + 3][lr] = av.w;
        Bs[k4 + 0][lr] = bv.x; Bs[k4 + 1][lr] = bv.y;
        Bs[k4 + 2][lr] = bv.z; Bs[k4 + 3][lr] = bv.w;
        __syncthreads();
#pragma unroll
        for (int dd = 0; dd < 16; ++dd) {
            float4 a4 = *(const float4*)&As[dd][ty << 2];
            float4 b4 = *(const float4*)&Bs[dd][tx << 2];
            float ar[4] = {a4.x, a4.y, a4.z, a4.w};
            float br[4] = {b4.x, b4.y, b4.z, b4.w};
#pragma unroll
            for (int i = 0; i < 4; ++i)
#pragma unroll
                for (int j = 0; j < 4; ++j)
                    acc[i][j] = fmaf(ar[i], br[j], acc[i][j]);
        }
        __syncthreads();
    }
#pragma unroll
    for (int i = 0; i < 4; ++i) {
        float4 o;
        const int c = c0 + (tx << 2);
        o.x = acc[i][0] + bias[c + 0];
        o.y = acc[i][1] + bias[c + 1];
        o.z = acc[i][2] + bias[c + 2];
        o.w = acc[i][3] + bias[c + 3];
        *(float4*)&C[(size_t)(r0 + (ty << 2) + i) * N + c] = o;
    }
}

__device__ __forceinline__ void tile_gemm_f32(
    const float* __restrict__ xb, int src, bool ok,
    const float* __restrict__ wrow,
    int lr, int k4, int tx, int ty,
    float (&As)[16][68], float (&Ws)[16][68], float (&acc)[4][4])
{
#pragma unroll
    for (int i = 0; i < 4; ++i)
#pragma unroll
        for (int j = 0; j < 4; ++j) acc[i][j] = 0.f;
    const float* xrow = xb + (size_t)(ok ? src : 0) * DM + k4;
    for (int d0 = 0; d0 < DM; d0 += 16) {
        float4 av = make_float4(0.f, 0.f, 0.f, 0.f);
        if (ok) av = *(const float4*)(xrow + d0);
        float4 wv = *(const float4*)(wrow + d0);
        As[k4 + 0][lr] = av.x; As[k4 + 1][lr] = av.y;
        As[k4 + 2][lr] = av.z; As[k4 + 3][lr] = av.w;
        Ws[k4 + 0][lr] = wv.x; Ws[k4 + 1][lr] = wv.y;
        Ws[k4 + 2][lr] = wv.z; Ws[k4 + 3][lr] = wv.w;
        __syncthreads();
#pragma unroll
        for (int dd = 0; dd < 16; ++dd) {
            float4 a4 = *(const float4*)&As[dd][ty << 2];
            float4 b4 = *(const float4*)&Ws[dd][tx << 2];
            float ar[4] = {a4.x, a4.y, a4.z, a4.w};
            float br[4] = {b4.x, b4.y, b4.z, b4.w};
#pragma unroll
            for (int i = 0; i < 4; ++i)
#pragma unroll
                for (int j = 0; j < 4; ++j)
                    acc[i][j] = fmaf(ar[i], br[j], acc[i][j]);
        }
        __syncthreads();
    }
}

__global__ __launch_bounds__(256, 2) void attn_kernel(
    const float* __restrict__ x, const float* __restrict__ q,
    const float* __restrict__ Wk, const float* __restrict__ bk,
    const float* __restrict__ Wv, const float* __restrict__ bv,
    float* __restrict__ attn)
{
    __shared__ float As[16][68];
    __shared__ float Ws[16][68];
    __shared__ float qs[64][68];
    __shared__ float lg[64][17];
    __shared__ float red[64][17];
    const int tid = threadIdx.x;
    const int tx = tid & 15, ty = tid >> 4;
    const int bid = blockIdx.x;
    const int h = bid & 7, t = (bid >> 3) & 15, b = bid >> 7;
    const int l0 = t << 6;
    const int dil = c_dil[h];
    const int lr = tid >> 2, k4 = (tid & 3) << 2;
    for (int i = tid; i < 64 * 16; i += 256) {
        int l = i >> 4, o4 = (i & 15) << 2;
        float4 v = *(const float4*)&q[((size_t)(b * LL + l0 + l) * HH + h) * HW + o4];
        *(float4*)&qs[l][o4] = v;
    }
    const float* xb  = x  + (size_t)b * LL * DM;
    const float* Wkh = Wk + (size_t)h * KT * HW * DM;
    const float* Wvh = Wv + (size_t)h * KT * HW * DM;
    const float* bkh = bk + h * KT * HW;
    const float* bvh = bv + h * KT * HW;
    float acc[4][4];
    for (int kk = 0; kk < KT; ++kk) {
        const int src = l0 + lr - (KT - 1 - kk) * dil;
        const bool ok = (src >= 0) && (src < LL);
        tile_gemm_f32(xb, src, ok, Wkh + (size_t)(kk * HW + lr) * DM + k4,
                      lr, k4, tx, ty, As, Ws, acc);
        const float* bkp = bkh + kk * HW + (tx << 2);
#pragma unroll
        for (int i = 0; i < 4; ++i) {
            float p = 0.f;
#pragma unroll
            for (int j = 0; j < 4; ++j)
                p += (acc[i][j] + bkp[j]) * qs[(ty << 2) + i][(tx << 2) + j];
            red[(ty << 2) + i][tx] = p;
        }
        __syncthreads();
        if (tid < 64) {
            float s = 0.f;
#pragma unroll
            for (int u = 0; u < 16; ++u) s += red[tid][u];
            lg[tid][kk] = s;
        }
        __syncthreads();
    }
    if (tid < 64) {
        float m = lg[tid][0];
#pragma unroll
        for (int u = 1; u < KT; ++u) m = fmaxf(m, lg[tid][u]);
        float s = 0.f;
#pragma unroll
        for (int u = 0; u < KT; ++u) {
            float e = expf(lg[tid][u] - m);
            lg[tid][u] = e; s += e;
        }
        float inv = 1.f / s;
#pragma unroll
        for (int u = 0; u < KT; ++u) lg[tid][u] *= inv;
    }
    __syncthreads();
    float vacc[4][4];
#pragma unroll
    for (int i = 0; i < 4; ++i)
#pragma unroll
        for (int j = 0; j < 4; ++j) vacc[i][j] = 0.f;
    for (int kk = 0; kk < KT; ++kk) {
        const int src = l0 + lr - (KT - 1 - kk) * dil;
        const bool ok = (src >= 0) && (src < LL);
        tile_gemm_f32(xb, src, ok, Wvh + (size_t)(kk * HW + lr) * DM + k4,
                      lr, k4, tx, ty, As, Ws, acc);
        const float* bvp = bvh + kk * HW + (tx << 2);
#pragma unroll
        for (int i = 0; i < 4; ++i) {
            float sc = lg[(ty << 2) + i][kk];
#pragma unroll
            for (int j = 0; j < 4; ++j)
                vacc[i][j] = fmaf(sc, acc[i][j] + bvp[j], vacc[i][j]);
        }
    }
#pragma unroll
    for (int i = 0; i < 4; ++i) {
        float4 o;
        o.x = vacc[i][0] * 0.125f;
        o.y = vacc[i][1] * 0.125f;
        o.z = vacc[i][2] * 0.125f;
        o.w = vacc[i][3] * 0.125f;
        *(float4*)&attn[((size_t)(b * LL + l0 + (ty << 2) + i) * HH + h) * HW + (tx << 2)] = o;
    }
}

// ===========================================================================
extern "C" void kernel_launch(void* const* d_in, const int* in_sizes, int n_in,
                              void* d_out, int out_size, void* d_ws, size_t ws_size,
                              hipStream_t stream)
{
    const float* x  = (const float*)d_in[0];
    const float* Wq = (const float*)d_in[1];
    const float* bq = (const float*)d_in[2];
    const float* Wk = (const float*)d_in[3];
    const float* bk = (const float*)d_in[4];
    const float* Wv = (const float*)d_in[5];
    const float* bv = (const float*)d_in[6];
    const float* Wo = (const float*)d_in[7];
    const float* bo = (const float*)d_in[8];
    float* out = (float*)d_out;

    const int M = BD * LL;  // 2048

    // ws layout (ushort elements) for the fast path
    const size_t N_X   = (size_t)BD * LL * DM;            //  1,048,576
    const size_t N_WB  = (size_t)NQKV * DM;               //  8,650,752
    const size_t N_WO  = (size_t)DM * DM;                 //    262,144
    const size_t N_QKV = (size_t)M * NQKV;                // 34,603,008
    const size_t NEED  = (N_X + N_WB + N_WO + N_QKV + N_X) * 2;

    if (ws_size >= NEED) {
        u16* xb    = (u16*)d_ws;
        u16* wb    = xb    + N_X;      // [Wq|Wk|Wv] swizzled, 16896 x 512
        u16* wob   = wb    + N_WB;
        u16* qkv   = wob   + N_WO;     // natural row-major 2048 x 16896
        u16* attnb = qkv   + N_QKV;

        cvt_swz<<<9728, 256, 0, stream>>>(x, Wq, Wk, Wv, Wo, xb, wb, wob);

        // qkv = x * [Wq|Wk|Wv]^T + bias (natural layout)
        gemm_bf16<<<dim3(136, 16), 256, 0, stream>>>(
            xb, wb, bq, bk, bv, qkv);

        // gather + softmax + weighted sum -> attnb (swizzled)
        attn_bf16<<<BD * HH * (LL / 32), 256, 0, stream>>>(
            qkv, bk, bv, attnb);

        // out = attnb * Wo^T + bo -> fp32
        gemm_out<<<dim3(8, 32), 256, 0, stream>>>(attnb, wob, bo, out);
    } else {
        // fp32 fallback (round-1 path, 8 MB ws)
        float* qws = (float*)d_ws;
        float* aws = qws + (size_t)BD * LL * HH * HW;
        gemm_nt_bias<<<dim3((HH * HW) / 64, M / 64), 256, 0, stream>>>(
            x, Wq, bq, qws, M, HH * HW, DM);
        attn_kernel<<<BD * HH * (LL / 64), 256, 0, stream>>>(
            x, qws, Wk, bk, Wv, bv, aws);
        gemm_nt_bias<<<dim3(DM / 64, M / 64), 256, 0, stream>>>(
            aws, Wo, bo, out, M, DM, HH * HW);
    }
}